// Round 1
// baseline (392.735 us; speedup 1.0000x reference)
//
#include <hip/hip_runtime.h>
#include <cstdint>
#include <cstddef>

typedef unsigned short u16;
typedef __attribute__((ext_vector_type(8))) short bf16x8;
typedef __attribute__((ext_vector_type(4))) float f32x4;

#define SCALE_ 0.125f

#define EPI_F32 0
#define EPI_BF16_RELU 1
#define EPI_QK 2
#define EPI_VT 3

__device__ __forceinline__ u16 f2bf(float f) {
  uint32_t u = __float_as_uint(f);
  return (u16)((u + 0x7FFFu + ((u >> 16) & 1u)) >> 16);
}

__device__ __forceinline__ void gload_lds16(const void* g, void* l) {
  __builtin_amdgcn_global_load_lds((const __attribute__((address_space(1))) void*)g,
                                   (__attribute__((address_space(3))) void*)l, 16, 0, 0);
}

// ---------------- fp32 -> bf16 convert (vectorized, 8 elems/thread) -------------
__global__ __launch_bounds__(256) void cvt_kernel(const float* __restrict__ in,
                                                  u16* __restrict__ out, int n8) {
  const int i = blockIdx.x * 256 + threadIdx.x;
  if (i >= n8) return;
  const float4* p = (const float4*)in + (size_t)i * 2;
  float4 a = p[0], b = p[1];
  union { u16 u[8]; uint4 q; } pk;
  pk.u[0] = f2bf(a.x); pk.u[1] = f2bf(a.y); pk.u[2] = f2bf(a.z); pk.u[3] = f2bf(a.w);
  pk.u[4] = f2bf(b.x); pk.u[5] = f2bf(b.y); pk.u[6] = f2bf(b.z); pk.u[7] = f2bf(b.w);
  ((uint4*)out)[i] = pk.q;
}

// ------------- fp32 W[K][N] -> bf16 Wt[N][K] (LDS-tiled transpose) --------------
__global__ __launch_bounds__(256) void tcvt_kernel(const float* __restrict__ W,
                                                   u16* __restrict__ Wt, int K, int N) {
  __shared__ float tl[32][33];
  const int t = threadIdx.x;
  const int kr0 = blockIdx.y * 32, nc0 = blockIdx.x * 32;
  const int r = t >> 3, cq = (t & 7) * 4;
  float4 v = *(const float4*)&W[(size_t)(kr0 + r) * N + nc0 + cq];
  tl[r][cq + 0] = v.x; tl[r][cq + 1] = v.y; tl[r][cq + 2] = v.z; tl[r][cq + 3] = v.w;
  __syncthreads();
  union { u16 u[4]; uint2 q; } pk;
#pragma unroll
  for (int j = 0; j < 4; ++j) pk.u[j] = f2bf(tl[cq + j][r]);
  *(uint2*)&Wt[(size_t)(nc0 + r) * K + kr0 + cq] = pk.q;
}

// ---------------------------- bf16 MFMA GEMM ------------------------------------
// C[M][N] = A[M][K] @ Bt[N][K]^T + bias, 128x128 tile, BK=32, 4 waves (2x2),
// wave computes 64x64 via 4x4 fragments of 16x16x32 MFMA. m97-style staging.
template<int EPI>
__global__ __launch_bounds__(256) void gemm_kernel(
    const u16* __restrict__ A, const u16* __restrict__ Bt,
    const float* __restrict__ bias, void* __restrict__ out,
    int M, int N, int K) {
  __shared__ u16 As[128 * 32];
  __shared__ u16 Bs[128 * 32];
  const int tid = threadIdx.x;
  const int lane = tid & 63;
  const int wave = tid >> 6;
  const int m0 = blockIdx.y * 128;
  const int n0 = blockIdx.x * 128;
  const int wm = wave >> 1, wn = wave & 1;
  const int g = lane >> 4, lr = lane & 15;
  const int srow = lane >> 2, scol = (lane & 3) * 8;

  f32x4 acc[4][4] = {};

  for (int k0 = 0; k0 < K; k0 += 32) {
#pragma unroll
    for (int i = 0; i < 2; ++i) {
      const int chunk = i * 4 + wave;  // 16-row chunk, linear LDS dest
      gload_lds16(A  + (size_t)(m0 + chunk * 16 + srow) * K + k0 + scol, &As[chunk * 512]);
      gload_lds16(Bt + (size_t)(n0 + chunk * 16 + srow) * K + k0 + scol, &Bs[chunk * 512]);
    }
    __syncthreads();  // compiler emits vmcnt(0) drain here
    bf16x8 a[4], b[4];
#pragma unroll
    for (int mi = 0; mi < 4; ++mi) a[mi] = *(const bf16x8*)&As[(wm * 64 + mi * 16 + lr) * 32 + g * 8];
#pragma unroll
    for (int ni = 0; ni < 4; ++ni) b[ni] = *(const bf16x8*)&Bs[(wn * 64 + ni * 16 + lr) * 32 + g * 8];
#pragma unroll
    for (int mi = 0; mi < 4; ++mi)
#pragma unroll
      for (int ni = 0; ni < 4; ++ni)
        acc[mi][ni] = __builtin_amdgcn_mfma_f32_16x16x32_bf16(a[mi], b[ni], acc[mi][ni], 0, 0, 0);
    __syncthreads();
  }

  // epilogue: D layout col=lane&15, row=(lane>>4)*4+reg  [m89-verified]
#pragma unroll
  for (int mi = 0; mi < 4; ++mi) {
#pragma unroll
    for (int ni = 0; ni < 4; ++ni) {
      const int col = n0 + wn * 64 + ni * 16 + lr;
      const float bv = bias[col];
      f32x4 v = acc[mi][ni];
#pragma unroll
      for (int r = 0; r < 4; ++r) {
        const int row = m0 + wm * 64 + mi * 16 + g * 4 + r;
        const float y = v[r] + bv;
        if (EPI == EPI_F32) {
          ((float*)out)[(size_t)row * N + col] = y;
        } else if (EPI == EPI_BF16_RELU) {
          ((u16*)out)[(size_t)row * N + col] = f2bf(fmaxf(y, 0.f));
        } else if (EPI == EPI_QK) {
          const int b = row >> 10, t = row & 1023, h = col >> 6, d = col & 63;
          ((u16*)out)[((size_t)((b * 8 + h) * 1024 + t)) * 64 + d] = f2bf(y);
        } else {  // EPI_VT: V transposed per head -> [BH][64][1024]
          const int b = row >> 10, t = row & 1023, h = col >> 6, d = col & 63;
          ((u16*)out)[((size_t)((b * 8 + h) * 64 + d)) * 1024 + t] = f2bf(y);
        }
      }
    }
  }
}

// ------------------------- flash attention (bf16 MFMA) --------------------------
// grid: (b,h,qtile64): 4 waves/block, wave owns 16 q rows; iterate 32-key tiles.
__global__ __launch_bounds__(256) void attn_kernel(
    const u16* __restrict__ Q, const u16* __restrict__ K,
    const u16* __restrict__ Vt, u16* __restrict__ ctx) {
  __shared__ u16 P[4 * 512];  // per-wave [16][32] bf16 P tile
  const int tid = threadIdx.x, lane = tid & 63, wave = tid >> 6;
  const int bh = blockIdx.x >> 4;
  const int qt = blockIdx.x & 15;
  const int q0 = qt * 64 + wave * 16;
  const int g = lane >> 4, lr = lane & 15;

  const u16* Qp = Q + ((size_t)bh * 1024 + q0) * 64;
  const bf16x8 qa0 = *(const bf16x8*)&Qp[lr * 64 + g * 8];
  const bf16x8 qa1 = *(const bf16x8*)&Qp[lr * 64 + 32 + g * 8];

  const u16* Kbp = K + (size_t)bh * 65536;
  const u16* Vbp = Vt + (size_t)bh * 65536;
  u16* Pw = &P[wave * 512];

  f32x4 acc[4] = {};
  float mrun[4] = {-1e30f, -1e30f, -1e30f, -1e30f};
  float lrun[4] = {0.f, 0.f, 0.f, 0.f};

  for (int kt = 0; kt < 32; ++kt) {
    const int key0 = kt * 32;
    f32x4 s[2];
#pragma unroll
    for (int kf = 0; kf < 2; ++kf) {
      const u16* Kp = Kbp + (size_t)(key0 + kf * 16 + lr) * 64;
      bf16x8 kv0 = *(const bf16x8*)&Kp[g * 8];
      bf16x8 kv1 = *(const bf16x8*)&Kp[32 + g * 8];
      f32x4 z = {};
      z = __builtin_amdgcn_mfma_f32_16x16x32_bf16(qa0, kv0, z, 0, 0, 0);
      s[kf] = __builtin_amdgcn_mfma_f32_16x16x32_bf16(qa1, kv1, z, 0, 0, 0);
    }
    float p0[4], p1[4], pm[4], rs[4], alpha[4];
#pragma unroll
    for (int r = 0; r < 4; ++r) {
      s[0][r] *= SCALE_; s[1][r] *= SCALE_;
      pm[r] = fmaxf(s[0][r], s[1][r]);
    }
#pragma unroll
    for (int off = 8; off >= 1; off >>= 1)
#pragma unroll
      for (int r = 0; r < 4; ++r) pm[r] = fmaxf(pm[r], __shfl_xor(pm[r], off));
#pragma unroll
    for (int r = 0; r < 4; ++r) {
      const float mn = fmaxf(mrun[r], pm[r]);
      alpha[r] = __expf(mrun[r] - mn);
      mrun[r] = mn;
      p0[r] = __expf(s[0][r] - mn);
      p1[r] = __expf(s[1][r] - mn);
      rs[r] = p0[r] + p1[r];
    }
#pragma unroll
    for (int off = 8; off >= 1; off >>= 1)
#pragma unroll
      for (int r = 0; r < 4; ++r) rs[r] += __shfl_xor(rs[r], off);
#pragma unroll
    for (int r = 0; r < 4; ++r) lrun[r] = lrun[r] * alpha[r] + rs[r];
#pragma unroll
    for (int df = 0; df < 4; ++df)
#pragma unroll
      for (int r = 0; r < 4; ++r) acc[df][r] *= alpha[r];
    // P (D-layout) -> LDS -> reload as A-layout (cross-lane transpose)
#pragma unroll
    for (int r = 0; r < 4; ++r) {
      Pw[(g * 4 + r) * 32 + lr] = f2bf(p0[r]);
      Pw[(g * 4 + r) * 32 + 16 + lr] = f2bf(p1[r]);
    }
    __syncthreads();
    const bf16x8 pa = *(const bf16x8*)&Pw[lr * 32 + g * 8];
#pragma unroll
    for (int df = 0; df < 4; ++df) {
      bf16x8 bv = *(const bf16x8*)&Vbp[(size_t)(df * 16 + lr) * 1024 + key0 + g * 8];
      acc[df] = __builtin_amdgcn_mfma_f32_16x16x32_bf16(pa, bv, acc[df], 0, 0, 0);
    }
    __syncthreads();
  }
  const int b = bh >> 3, h = bh & 7;
#pragma unroll
  for (int df = 0; df < 4; ++df) {
#pragma unroll
    for (int r = 0; r < 4; ++r) {
      const int qrow = q0 + g * 4 + r;
      const float y = acc[df][r] / lrun[r];
      ctx[((size_t)(b * 1024 + qrow)) * 512 + h * 64 + df * 16 + lr] = f2bf(y);
    }
  }
}

// ----------------- residual + layernorm (1 wave per 512-col row) ----------------
__global__ __launch_bounds__(256) void ln_kernel(
    const float* __restrict__ A, const float* __restrict__ R,
    const float* __restrict__ gw, const float* __restrict__ bw,
    float* __restrict__ outF, u16* __restrict__ outB) {
  const int lane = threadIdx.x & 63, wave = threadIdx.x >> 6;
  const int row = blockIdx.x * 4 + wave;
  const float4* a4 = (const float4*)(A + (size_t)row * 512);
  const float4* r4 = (const float4*)(R + (size_t)row * 512);
  float4 x0 = a4[lane * 2], x1 = a4[lane * 2 + 1];
  float4 y0 = r4[lane * 2], y1 = r4[lane * 2 + 1];
  float v[8] = {x0.x + y0.x, x0.y + y0.y, x0.z + y0.z, x0.w + y0.w,
                x1.x + y1.x, x1.y + y1.y, x1.z + y1.z, x1.w + y1.w};
  float s = 0.f;
#pragma unroll
  for (int j = 0; j < 8; ++j) s += v[j];
#pragma unroll
  for (int off = 32; off >= 1; off >>= 1) s += __shfl_xor(s, off);
  const float mu = s * (1.f / 512.f);
  float vs = 0.f;
#pragma unroll
  for (int j = 0; j < 8; ++j) { const float d = v[j] - mu; vs += d * d; }
#pragma unroll
  for (int off = 32; off >= 1; off >>= 1) vs += __shfl_xor(vs, off);
  const float rstd = rsqrtf(vs * (1.f / 512.f) + 1e-5f);
  float4 gA = ((const float4*)gw)[lane * 2], gB = ((const float4*)gw)[lane * 2 + 1];
  float4 bA = ((const float4*)bw)[lane * 2], bB = ((const float4*)bw)[lane * 2 + 1];
  const float og[8] = {gA.x, gA.y, gA.z, gA.w, gB.x, gB.y, gB.z, gB.w};
  const float ob[8] = {bA.x, bA.y, bA.z, bA.w, bB.x, bB.y, bB.z, bB.w};
  float o[8];
#pragma unroll
  for (int j = 0; j < 8; ++j) o[j] = (v[j] - mu) * rstd * og[j] + ob[j];
  float4 w0 = {o[0], o[1], o[2], o[3]}, w1 = {o[4], o[5], o[6], o[7]};
  ((float4*)(outF + (size_t)row * 512))[lane * 2] = w0;
  ((float4*)(outF + (size_t)row * 512))[lane * 2 + 1] = w1;
  if (outB) {
    union { u16 u[8]; uint4 q; } pk;
#pragma unroll
    for (int j = 0; j < 8; ++j) pk.u[j] = f2bf(o[j]);
    ((uint4*)(outB + (size_t)row * 512))[lane] = pk.q;
  }
}

// --------------------------------- launch ---------------------------------------
extern "C" void kernel_launch(void* const* d_in, const int* in_sizes, int n_in,
                              void* d_out, int out_size, void* d_ws, size_t ws_size,
                              hipStream_t stream) {
  const float* x   = (const float*)d_in[0];
  const float* Wq  = (const float*)d_in[1];
  const float* bq  = (const float*)d_in[2];
  const float* Wk  = (const float*)d_in[3];
  const float* bk  = (const float*)d_in[4];
  const float* Wv  = (const float*)d_in[5];
  const float* bv  = (const float*)d_in[6];
  const float* Wo  = (const float*)d_in[7];
  const float* bo  = (const float*)d_in[8];
  const float* g1  = (const float*)d_in[9];
  const float* b1  = (const float*)d_in[10];
  const float* g2  = (const float*)d_in[11];
  const float* b2  = (const float*)d_in[12];
  const float* W1  = (const float*)d_in[13];
  const float* bf1 = (const float*)d_in[14];
  const float* W2  = (const float*)d_in[15];
  const float* bf2 = (const float*)d_in[16];

  char* ws = (char*)d_ws;
  u16*   xb      = (u16*)(ws + 0);           //  8192x512  bf16  (8.39 MB)
  u16*   Wqt     = (u16*)(ws + 8388608);
  u16*   Wkt     = (u16*)(ws + 8912896);
  u16*   Wvt     = (u16*)(ws + 9437184);
  u16*   Wot     = (u16*)(ws + 9961472);
  u16*   W1t     = (u16*)(ws + 10485760);    //  [2048][512]
  u16*   W2t     = (u16*)(ws + 12582912);    //  [512][2048]
  u16*   Qb      = (u16*)(ws + 14680064);    //  [BH][1024][64]
  u16*   Kb      = (u16*)(ws + 23068672);
  u16*   Vtb     = (u16*)(ws + 31457280);    //  [BH][64][1024]
  u16*   ctx     = (u16*)(ws + 39845888);    //  [8192][512] bf16
  float* attnout = (float*)(ws + 48234496);  //  [8192][512] f32
  float* h1f     = (float*)(ws + 65011712);  //  [8192][512] f32
  u16*   h1b     = (u16*)(ws + 81788928);    //  [8192][512] bf16
  u16*   mid     = (u16*)(ws + 31457280);    //  [8192][2048] bf16, aliases Vtb/ctx/attnout (dead by then)

  // convert inputs to bf16 (weights transposed to [N][K])
  cvt_kernel<<<2048, 256, 0, stream>>>(x, xb, 524288);
  tcvt_kernel<<<dim3(16, 16), 256, 0, stream>>>(Wq, Wqt, 512, 512);
  tcvt_kernel<<<dim3(16, 16), 256, 0, stream>>>(Wk, Wkt, 512, 512);
  tcvt_kernel<<<dim3(16, 16), 256, 0, stream>>>(Wv, Wvt, 512, 512);
  tcvt_kernel<<<dim3(16, 16), 256, 0, stream>>>(Wo, Wot, 512, 512);
  tcvt_kernel<<<dim3(64, 16), 256, 0, stream>>>(W1, W1t, 512, 2048);
  tcvt_kernel<<<dim3(16, 64), 256, 0, stream>>>(W2, W2t, 2048, 512);

  // projections
  gemm_kernel<EPI_QK><<<dim3(4, 64), 256, 0, stream>>>(xb, Wqt, bq, Qb, 8192, 512, 512);
  gemm_kernel<EPI_QK><<<dim3(4, 64), 256, 0, stream>>>(xb, Wkt, bk, Kb, 8192, 512, 512);
  gemm_kernel<EPI_VT><<<dim3(4, 64), 256, 0, stream>>>(xb, Wvt, bv, Vtb, 8192, 512, 512);

  attn_kernel<<<1024, 256, 0, stream>>>(Qb, Kb, Vtb, ctx);

  gemm_kernel<EPI_F32><<<dim3(4, 64), 256, 0, stream>>>(ctx, Wot, bo, attnout, 8192, 512, 512);
  ln_kernel<<<2048, 256, 0, stream>>>(x, attnout, g1, b1, h1f, h1b);

  gemm_kernel<EPI_BF16_RELU><<<dim3(16, 64), 256, 0, stream>>>(h1b, W1t, bf1, mid, 8192, 2048, 512);
  gemm_kernel<EPI_F32><<<dim3(4, 64), 256, 0, stream>>>(mid, W2t, bf2, (float*)d_out, 8192, 512, 2048);
  ln_kernel<<<2048, 256, 0, stream>>>(h1f, (const float*)d_out, g2, b2, (float*)d_out, nullptr);
}

// Round 2
// 335.948 us; speedup vs baseline: 1.1690x; 1.1690x over previous
//
#include <hip/hip_runtime.h>
#include <cstdint>
#include <cstddef>

typedef unsigned short u16;
typedef __attribute__((ext_vector_type(8))) short bf16x8;
typedef __attribute__((ext_vector_type(4))) float f32x4;
typedef __attribute__((ext_vector_type(16))) float f32x16;

#define EPI_F32 0
#define EPI_BF16_RELU 1
#define EPI_QK 2
#define EPI_VT 3
#define EPI_QS 4   // like EPI_QK but scaled by 1/sqrt(D)

__device__ __forceinline__ u16 f2bf(float f) {
  uint32_t u = __float_as_uint(f);
  return (u16)((u + 0x7FFFu + ((u >> 16) & 1u)) >> 16);
}

__device__ __forceinline__ uint32_t cvt_pk_bf16(float lo, float hi) {
  uint32_t r;
  asm("v_cvt_pk_bf16_f32 %0, %1, %2" : "=v"(r) : "v"(lo), "v"(hi));
  return r;
}

__device__ __forceinline__ void gload_lds16(const void* g, void* l) {
  __builtin_amdgcn_global_load_lds((const __attribute__((address_space(1))) void*)g,
                                   (__attribute__((address_space(3))) void*)l, 16, 0, 0);
}

// ---------------- fp32 -> bf16 convert (vectorized, 8 elems/thread) -------------
__global__ __launch_bounds__(256) void cvt_kernel(const float* __restrict__ in,
                                                  u16* __restrict__ out, int n8) {
  const int i = blockIdx.x * 256 + threadIdx.x;
  if (i >= n8) return;
  const float4* p = (const float4*)in + (size_t)i * 2;
  float4 a = p[0], b = p[1];
  union { u16 u[8]; uint4 q; } pk;
  pk.u[0] = f2bf(a.x); pk.u[1] = f2bf(a.y); pk.u[2] = f2bf(a.z); pk.u[3] = f2bf(a.w);
  pk.u[4] = f2bf(b.x); pk.u[5] = f2bf(b.y); pk.u[6] = f2bf(b.z); pk.u[7] = f2bf(b.w);
  ((uint4*)out)[i] = pk.q;
}

// ------------- fp32 W[K][N] -> bf16 Wt[N][K] (LDS-tiled transpose) --------------
__global__ __launch_bounds__(256) void tcvt_kernel(const float* __restrict__ W,
                                                   u16* __restrict__ Wt, int K, int N) {
  __shared__ float tl[32][33];
  const int t = threadIdx.x;
  const int kr0 = blockIdx.y * 32, nc0 = blockIdx.x * 32;
  const int r = t >> 3, cq = (t & 7) * 4;
  float4 v = *(const float4*)&W[(size_t)(kr0 + r) * N + nc0 + cq];
  tl[r][cq + 0] = v.x; tl[r][cq + 1] = v.y; tl[r][cq + 2] = v.z; tl[r][cq + 3] = v.w;
  __syncthreads();
  union { u16 u[4]; uint2 q; } pk;
#pragma unroll
  for (int j = 0; j < 4; ++j) pk.u[j] = f2bf(tl[cq + j][r]);
  *(uint2*)&Wt[(size_t)(nc0 + r) * K + kr0 + cq] = pk.q;
}

// ---------------------------- bf16 MFMA GEMM ------------------------------------
// C[M][N] = A[M][K] @ Bt[N][K]^T + bias, 128x128 tile, BK=32, 4 waves (2x2),
// wave computes 64x64 via 4x4 fragments of 16x16x32 MFMA. m97-style staging.
template<int EPI>
__global__ __launch_bounds__(256) void gemm_kernel(
    const u16* __restrict__ A, const u16* __restrict__ Bt,
    const float* __restrict__ bias, void* __restrict__ out,
    int M, int N, int K) {
  __shared__ u16 As[128 * 32];
  __shared__ u16 Bs[128 * 32];
  const int tid = threadIdx.x;
  const int lane = tid & 63;
  const int wave = tid >> 6;
  const int m0 = blockIdx.y * 128;
  const int n0 = blockIdx.x * 128;
  const int wm = wave >> 1, wn = wave & 1;
  const int g = lane >> 4, lr = lane & 15;
  const int srow = lane >> 2, scol = (lane & 3) * 8;

  f32x4 acc[4][4] = {};

  for (int k0 = 0; k0 < K; k0 += 32) {
#pragma unroll
    for (int i = 0; i < 2; ++i) {
      const int chunk = i * 4 + wave;  // 16-row chunk, linear LDS dest
      gload_lds16(A  + (size_t)(m0 + chunk * 16 + srow) * K + k0 + scol, &As[chunk * 512]);
      gload_lds16(Bt + (size_t)(n0 + chunk * 16 + srow) * K + k0 + scol, &Bs[chunk * 512]);
    }
    __syncthreads();  // compiler emits vmcnt(0) drain here
    bf16x8 a[4], b[4];
#pragma unroll
    for (int mi = 0; mi < 4; ++mi) a[mi] = *(const bf16x8*)&As[(wm * 64 + mi * 16 + lr) * 32 + g * 8];
#pragma unroll
    for (int ni = 0; ni < 4; ++ni) b[ni] = *(const bf16x8*)&Bs[(wn * 64 + ni * 16 + lr) * 32 + g * 8];
#pragma unroll
    for (int mi = 0; mi < 4; ++mi)
#pragma unroll
      for (int ni = 0; ni < 4; ++ni)
        acc[mi][ni] = __builtin_amdgcn_mfma_f32_16x16x32_bf16(a[mi], b[ni], acc[mi][ni], 0, 0, 0);
    __syncthreads();
  }

  // epilogue: D layout col=lane&15, row=(lane>>4)*4+reg  [m89-verified]
#pragma unroll
  for (int mi = 0; mi < 4; ++mi) {
#pragma unroll
    for (int ni = 0; ni < 4; ++ni) {
      const int col = n0 + wn * 64 + ni * 16 + lr;
      const float bv = bias[col];
      f32x4 v = acc[mi][ni];
#pragma unroll
      for (int r = 0; r < 4; ++r) {
        const int row = m0 + wm * 64 + mi * 16 + g * 4 + r;
        const float y = v[r] + bv;
        if (EPI == EPI_F32) {
          ((float*)out)[(size_t)row * N + col] = y;
        } else if (EPI == EPI_BF16_RELU) {
          ((u16*)out)[(size_t)row * N + col] = f2bf(fmaxf(y, 0.f));
        } else if (EPI == EPI_QK) {
          const int b = row >> 10, t = row & 1023, h = col >> 6, d = col & 63;
          ((u16*)out)[((size_t)((b * 8 + h) * 1024 + t)) * 64 + d] = f2bf(y);
        } else if (EPI == EPI_QS) {
          const int b = row >> 10, t = row & 1023, h = col >> 6, d = col & 63;
          ((u16*)out)[((size_t)((b * 8 + h) * 1024 + t)) * 64 + d] = f2bf(y * 0.125f);
        } else {  // EPI_VT: V transposed per head -> [BH][64][1024]
          const int b = row >> 10, t = row & 1023, h = col >> 6, d = col & 63;
          ((u16*)out)[((size_t)((b * 8 + h) * 64 + d)) * 1024 + t] = f2bf(y);
        }
      }
    }
  }
}

// ------------------- flash attention v2: swapped QK^T, 32x32 MFMA ---------------
// grid: 64 bh x 8 q-blocks(128 rows); 4 waves/block, wave owns 32 q rows.
// S' = mfma32(A=K, B=Q)  -> lane holds q-col = lane&31, 16 key-rows in regs.
// Softmax fully in-register (partner exchange via shfl_xor 32). PV computes
// ctx^T = mfma32(A=V^T, B=Pbf16). Epilogue: LDS chunk-XOR transpose -> ctx.
__global__ __launch_bounds__(256) void attn2_kernel(
    const u16* __restrict__ Q, const u16* __restrict__ K,
    const u16* __restrict__ Vt, u16* __restrict__ ctx) {
  __shared__ u16 tl[4 * 2048];
  const int tid = threadIdx.x, lane = tid & 63, w = tid >> 6;
  const int bh = blockIdx.x >> 3, qb = blockIdx.x & 7;
  const int c = lane & 31, g = lane >> 5;
  const int q0 = qb * 128 + w * 32;

  // Q fragments (B-operand): col=c -> row q0+c, kk = 16s + 8g + j
  const u16* Qp = Q + ((size_t)bh * 1024 + q0 + c) * 64 + g * 8;
  const bf16x8 qf0 = *(const bf16x8*)(Qp);
  const bf16x8 qf1 = *(const bf16x8*)(Qp + 16);
  const bf16x8 qf2 = *(const bf16x8*)(Qp + 32);
  const bf16x8 qf3 = *(const bf16x8*)(Qp + 48);

  const u16* Kbase = K + (size_t)bh * 65536;
  const u16* Vbase = Vt + (size_t)bh * 65536;

  f32x16 cacc[2] = {};
  float mrun = -1e30f, lrun = 0.f;

  // preload K tile 0 (A-operand: row = key0+c, kk = 16s + 8g + j)
  const u16* Kp0 = Kbase + (size_t)c * 64 + g * 8;
  bf16x8 kf0 = *(const bf16x8*)(Kp0);
  bf16x8 kf1 = *(const bf16x8*)(Kp0 + 16);
  bf16x8 kf2 = *(const bf16x8*)(Kp0 + 32);
  bf16x8 kf3 = *(const bf16x8*)(Kp0 + 48);

  for (int kt = 0; kt < 32; ++kt) {
    const int key0 = kt * 32;
    const int keyn = ((kt + 1) & 31) * 32;
    // V loads for this tile (A-operand of PV: row d = 32*h2 + c, kk along keys)
    const u16* Vp = Vbase + (size_t)c * 1024 + key0 + g * 8;
    const bf16x8 v00 = *(const bf16x8*)(Vp);
    const bf16x8 v01 = *(const bf16x8*)(Vp + 16);
    const bf16x8 v10 = *(const bf16x8*)(Vp + 32 * 1024);
    const bf16x8 v11 = *(const bf16x8*)(Vp + 32 * 1024 + 16);
    // prefetch next K tile
    const u16* Kpn = Kbase + (size_t)(keyn + c) * 64 + g * 8;
    const bf16x8 n0 = *(const bf16x8*)(Kpn);
    const bf16x8 n1 = *(const bf16x8*)(Kpn + 16);
    const bf16x8 n2 = *(const bf16x8*)(Kpn + 32);
    const bf16x8 n3 = *(const bf16x8*)(Kpn + 48);

    // QK^T (swapped): S'[key][q], D-layout col=q=c, key=(r&3)+8*(r>>2)+4g
    f32x16 sa = {};
    sa = __builtin_amdgcn_mfma_f32_32x32x16_bf16(kf0, qf0, sa, 0, 0, 0);
    sa = __builtin_amdgcn_mfma_f32_32x32x16_bf16(kf1, qf1, sa, 0, 0, 0);
    sa = __builtin_amdgcn_mfma_f32_32x32x16_bf16(kf2, qf2, sa, 0, 0, 0);
    sa = __builtin_amdgcn_mfma_f32_32x32x16_bf16(kf3, qf3, sa, 0, 0, 0);

    // online softmax, fully in-register
    float m_t = sa[0];
#pragma unroll
    for (int r = 1; r < 16; ++r) m_t = fmaxf(m_t, sa[r]);
    m_t = fmaxf(m_t, __shfl_xor(m_t, 32));
    const float mnew = fmaxf(mrun, m_t);
    const float alpha = __expf(mrun - mnew);
    mrun = mnew;
    float pv[16];
#pragma unroll
    for (int r = 0; r < 16; ++r) pv[r] = __expf(sa[r] - mnew);
    float ts = 0.f;
#pragma unroll
    for (int r = 0; r < 16; ++r) ts += pv[r];
    ts += __shfl_xor(ts, 32);
    lrun = lrun * alpha + ts;
#pragma unroll
    for (int r = 0; r < 16; ++r) { cacc[0][r] *= alpha; cacc[1][r] *= alpha; }

    // pack P -> bf16 pairs: wd[i] = keys {4g + 8*(i>>1) + 2*(i&1), +1}
    uint32_t wd[8], pw[8];
#pragma unroll
    for (int i = 0; i < 8; ++i) wd[i] = cvt_pk_bf16(pv[2 * i], pv[2 * i + 1]);
#pragma unroll
    for (int i = 0; i < 8; ++i) pw[i] = __shfl_xor((int)wd[i], 32);
    // B-fragments: step0 keys 8g+0..7, step1 keys 16+8g+0..7
    union { uint32_t u[4]; bf16x8 v; } b0, b1;
    const bool glo = (g == 0);
    b0.u[0] = glo ? wd[0] : pw[2]; b0.u[1] = glo ? wd[1] : pw[3];
    b0.u[2] = glo ? pw[0] : wd[2]; b0.u[3] = glo ? pw[1] : wd[3];
    b1.u[0] = glo ? wd[4] : pw[6]; b1.u[1] = glo ? wd[5] : pw[7];
    b1.u[2] = glo ? pw[4] : wd[6]; b1.u[3] = glo ? pw[5] : wd[7];

    // PV: ctx^T[d][q] accumulate
    cacc[0] = __builtin_amdgcn_mfma_f32_32x32x16_bf16(v00, b0.v, cacc[0], 0, 0, 0);
    cacc[0] = __builtin_amdgcn_mfma_f32_32x32x16_bf16(v01, b1.v, cacc[0], 0, 0, 0);
    cacc[1] = __builtin_amdgcn_mfma_f32_32x32x16_bf16(v10, b0.v, cacc[1], 0, 0, 0);
    cacc[1] = __builtin_amdgcn_mfma_f32_32x32x16_bf16(v11, b1.v, cacc[1], 0, 0, 0);

    kf0 = n0; kf1 = n1; kf2 = n2; kf3 = n3;
  }

  // epilogue: normalize, transpose via chunk-XOR-swizzled LDS, coalesced store
  const float inv = 1.0f / lrun;
  u16* tw = &tl[w * 2048];
#pragma unroll
  for (int h2 = 0; h2 < 2; ++h2) {
#pragma unroll
    for (int rq = 0; rq < 4; ++rq) {
      const u16 x0 = f2bf(cacc[h2][4 * rq + 0] * inv);
      const u16 x1 = f2bf(cacc[h2][4 * rq + 1] * inv);
      const u16 x2 = f2bf(cacc[h2][4 * rq + 2] * inv);
      const u16 x3 = f2bf(cacc[h2][4 * rq + 3] * inv);
      uint2 val;
      val.x = (uint32_t)x0 | ((uint32_t)x1 << 16);
      val.y = (uint32_t)x2 | ((uint32_t)x3 << 16);
      const int chunk = h2 * 4 + rq;  // d = chunk*8 + 4g + e
      *(uint2*)&tw[c * 64 + ((chunk ^ (c & 7)) * 8) + 4 * g] = val;
    }
  }
  __syncthreads();
  const int b_ = bh >> 3, h_ = bh & 7;
#pragma unroll
  for (int t = 0; t < 4; ++t) {
    const int lcg = t * 256 + tid;
    const int wv = lcg >> 8, rem = lcg & 255;
    const int q = rem >> 3, cg = rem & 7;
    const uint4 val = *(const uint4*)&tl[wv * 2048 + q * 64 + ((cg ^ (q & 7)) * 8)];
    const int grow = qb * 128 + wv * 32 + q;
    *(uint4*)&ctx[((size_t)(b_ * 1024 + grow)) * 512 + h_ * 64 + cg * 8] = val;
  }
}

// ----------------- residual + layernorm (1 wave per 512-col row) ----------------
__global__ __launch_bounds__(256) void ln_kernel(
    const float* __restrict__ A, const float* __restrict__ R,
    const float* __restrict__ gw, const float* __restrict__ bw,
    float* __restrict__ outF, u16* __restrict__ outB) {
  const int lane = threadIdx.x & 63, wave = threadIdx.x >> 6;
  const int row = blockIdx.x * 4 + wave;
  const float4* a4 = (const float4*)(A + (size_t)row * 512);
  const float4* r4 = (const float4*)(R + (size_t)row * 512);
  float4 x0 = a4[lane * 2], x1 = a4[lane * 2 + 1];
  float4 y0 = r4[lane * 2], y1 = r4[lane * 2 + 1];
  float v[8] = {x0.x + y0.x, x0.y + y0.y, x0.z + y0.z, x0.w + y0.w,
                x1.x + y1.x, x1.y + y1.y, x1.z + y1.z, x1.w + y1.w};
  float s = 0.f;
#pragma unroll
  for (int j = 0; j < 8; ++j) s += v[j];
#pragma unroll
  for (int off = 32; off >= 1; off >>= 1) s += __shfl_xor(s, off);
  const float mu = s * (1.f / 512.f);
  float vs = 0.f;
#pragma unroll
  for (int j = 0; j < 8; ++j) { const float d = v[j] - mu; vs += d * d; }
#pragma unroll
  for (int off = 32; off >= 1; off >>= 1) vs += __shfl_xor(vs, off);
  const float rstd = rsqrtf(vs * (1.f / 512.f) + 1e-5f);
  float4 gA = ((const float4*)gw)[lane * 2], gB = ((const float4*)gw)[lane * 2 + 1];
  float4 bA = ((const float4*)bw)[lane * 2], bB = ((const float4*)bw)[lane * 2 + 1];
  const float og[8] = {gA.x, gA.y, gA.z, gA.w, gB.x, gB.y, gB.z, gB.w};
  const float ob[8] = {bA.x, bA.y, bA.z, bA.w, bB.x, bB.y, bB.z, bB.w};
  float o[8];
#pragma unroll
  for (int j = 0; j < 8; ++j) o[j] = (v[j] - mu) * rstd * og[j] + ob[j];
  float4 w0 = {o[0], o[1], o[2], o[3]}, w1 = {o[4], o[5], o[6], o[7]};
  ((float4*)(outF + (size_t)row * 512))[lane * 2] = w0;
  ((float4*)(outF + (size_t)row * 512))[lane * 2 + 1] = w1;
  if (outB) {
    union { u16 u[8]; uint4 q; } pk;
#pragma unroll
    for (int j = 0; j < 8; ++j) pk.u[j] = f2bf(o[j]);
    ((uint4*)(outB + (size_t)row * 512))[lane] = pk.q;
  }
}

// --------------------------------- launch ---------------------------------------
extern "C" void kernel_launch(void* const* d_in, const int* in_sizes, int n_in,
                              void* d_out, int out_size, void* d_ws, size_t ws_size,
                              hipStream_t stream) {
  const float* x   = (const float*)d_in[0];
  const float* Wq  = (const float*)d_in[1];
  const float* bq  = (const float*)d_in[2];
  const float* Wk  = (const float*)d_in[3];
  const float* bk  = (const float*)d_in[4];
  const float* Wv  = (const float*)d_in[5];
  const float* bv  = (const float*)d_in[6];
  const float* Wo  = (const float*)d_in[7];
  const float* bo  = (const float*)d_in[8];
  const float* g1  = (const float*)d_in[9];
  const float* b1  = (const float*)d_in[10];
  const float* g2  = (const float*)d_in[11];
  const float* b2  = (const float*)d_in[12];
  const float* W1  = (const float*)d_in[13];
  const float* bf1 = (const float*)d_in[14];
  const float* W2  = (const float*)d_in[15];
  const float* bf2 = (const float*)d_in[16];

  char* ws = (char*)d_ws;
  u16*   xb      = (u16*)(ws + 0);           //  8192x512  bf16  (8.39 MB)
  u16*   Wqt     = (u16*)(ws + 8388608);
  u16*   Wkt     = (u16*)(ws + 8912896);
  u16*   Wvt     = (u16*)(ws + 9437184);
  u16*   Wot     = (u16*)(ws + 9961472);
  u16*   W1t     = (u16*)(ws + 10485760);    //  [2048][512]
  u16*   W2t     = (u16*)(ws + 12582912);    //  [512][2048]
  u16*   Qb      = (u16*)(ws + 14680064);    //  [BH][1024][64]
  u16*   Kb      = (u16*)(ws + 23068672);
  u16*   Vtb     = (u16*)(ws + 31457280);    //  [BH][64][1024]
  u16*   ctx     = (u16*)(ws + 39845888);    //  [8192][512] bf16
  float* attnout = (float*)(ws + 48234496);  //  [8192][512] f32
  float* h1f     = (float*)(ws + 65011712);  //  [8192][512] f32
  u16*   h1b     = (u16*)(ws + 81788928);    //  [8192][512] bf16
  u16*   mid     = (u16*)(ws + 31457280);    //  [8192][2048] bf16, aliases Vtb/ctx/attnout (dead by then)

  // convert inputs to bf16 (weights transposed to [N][K])
  cvt_kernel<<<2048, 256, 0, stream>>>(x, xb, 524288);
  tcvt_kernel<<<dim3(16, 16), 256, 0, stream>>>(Wq, Wqt, 512, 512);
  tcvt_kernel<<<dim3(16, 16), 256, 0, stream>>>(Wk, Wkt, 512, 512);
  tcvt_kernel<<<dim3(16, 16), 256, 0, stream>>>(Wv, Wvt, 512, 512);
  tcvt_kernel<<<dim3(16, 16), 256, 0, stream>>>(Wo, Wot, 512, 512);
  tcvt_kernel<<<dim3(64, 16), 256, 0, stream>>>(W1, W1t, 512, 2048);
  tcvt_kernel<<<dim3(16, 64), 256, 0, stream>>>(W2, W2t, 2048, 512);

  // projections (Q pre-scaled by 1/sqrt(D))
  gemm_kernel<EPI_QS><<<dim3(4, 64), 256, 0, stream>>>(xb, Wqt, bq, Qb, 8192, 512, 512);
  gemm_kernel<EPI_QK><<<dim3(4, 64), 256, 0, stream>>>(xb, Wkt, bk, Kb, 8192, 512, 512);
  gemm_kernel<EPI_VT><<<dim3(4, 64), 256, 0, stream>>>(xb, Wvt, bv, Vtb, 8192, 512, 512);

  attn2_kernel<<<512, 256, 0, stream>>>(Qb, Kb, Vtb, ctx);

  gemm_kernel<EPI_F32><<<dim3(4, 64), 256, 0, stream>>>(ctx, Wot, bo, attnout, 8192, 512, 512);
  ln_kernel<<<2048, 256, 0, stream>>>(x, attnout, g1, b1, h1f, h1b);

  gemm_kernel<EPI_BF16_RELU><<<dim3(16, 64), 256, 0, stream>>>(h1b, W1t, bf1, mid, 8192, 2048, 512);
  gemm_kernel<EPI_F32><<<dim3(4, 64), 256, 0, stream>>>(mid, W2t, bf2, (float*)d_out, 8192, 512, 2048);
  ln_kernel<<<2048, 256, 0, stream>>>(h1f, (const float*)d_out, g2, b2, (float*)d_out, nullptr);
}

// Round 4
// 319.994 us; speedup vs baseline: 1.2273x; 1.0499x over previous
//
#include <hip/hip_runtime.h>
#include <cstdint>
#include <cstddef>

typedef unsigned short u16;
typedef __attribute__((ext_vector_type(8))) short bf16x8;
typedef __attribute__((ext_vector_type(4))) float f32x4;
typedef __attribute__((ext_vector_type(16))) float f32x16;

#define EPI_F32 0
#define EPI_BF16_RELU 1
#define EPI_QKV 2

// 1/sqrt(64) * log2(e): QK^T scores come out in log2 domain -> exp2 softmax
#define QSCALE 0.18033688011112042f

__device__ __forceinline__ u16 f2bf(float f) {
  uint32_t u = __float_as_uint(f);
  return (u16)((u + 0x7FFFu + ((u >> 16) & 1u)) >> 16);
}

__device__ __forceinline__ uint32_t cvt_pk_bf16(float lo, float hi) {
  uint32_t r;
  asm("v_cvt_pk_bf16_f32 %0, %1, %2" : "=v"(r) : "v"(lo), "v"(hi));
  return r;
}

__device__ __forceinline__ float fexp2(float x) { return __builtin_amdgcn_exp2f(x); }

__device__ __forceinline__ void gload_lds16(const void* g, void* l) {
  __builtin_amdgcn_global_load_lds((const __attribute__((address_space(1))) void*)g,
                                   (__attribute__((address_space(3))) void*)l, 16, 0, 0);
}

// ---------------- fp32 -> bf16 convert (vectorized, 8 elems/thread) -------------
__global__ __launch_bounds__(256) void cvt_kernel(const float* __restrict__ in,
                                                  u16* __restrict__ out, int n8) {
  const int i = blockIdx.x * 256 + threadIdx.x;
  if (i >= n8) return;
  const float4* p = (const float4*)in + (size_t)i * 2;
  float4 a = p[0], b = p[1];
  union { u16 u[8]; uint4 q; } pk;
  pk.u[0] = f2bf(a.x); pk.u[1] = f2bf(a.y); pk.u[2] = f2bf(a.z); pk.u[3] = f2bf(a.w);
  pk.u[4] = f2bf(b.x); pk.u[5] = f2bf(b.y); pk.u[6] = f2bf(b.z); pk.u[7] = f2bf(b.w);
  ((uint4*)out)[i] = pk.q;
}

// ------------- fp32 W[K][N] -> bf16 Wt[N][K] (LDS-tiled transpose) --------------
__global__ __launch_bounds__(256) void tcvt_kernel(const float* __restrict__ W,
                                                   u16* __restrict__ Wt, int K, int N) {
  __shared__ float tl[32][33];
  const int t = threadIdx.x;
  const int kr0 = blockIdx.y * 32, nc0 = blockIdx.x * 32;
  const int r = t >> 3, cq = (t & 7) * 4;
  float4 v = *(const float4*)&W[(size_t)(kr0 + r) * N + nc0 + cq];
  tl[r][cq + 0] = v.x; tl[r][cq + 1] = v.y; tl[r][cq + 2] = v.z; tl[r][cq + 3] = v.w;
  __syncthreads();
  union { u16 u[4]; uint2 q; } pk;
#pragma unroll
  for (int j = 0; j < 4; ++j) pk.u[j] = f2bf(tl[cq + j][r]);
  *(uint2*)&Wt[(size_t)(nc0 + r) * K + kr0 + cq] = pk.q;
}

// ---------------- pack bq|bk|bv into one contiguous 1536-float bias -------------
__global__ __launch_bounds__(256) void packb_kernel(const float* __restrict__ bq,
                                                    const float* __restrict__ bk,
                                                    const float* __restrict__ bv,
                                                    float* __restrict__ out) {
  const int i = blockIdx.x * 256 + threadIdx.x;
  if (i >= 1536) return;
  out[i] = i < 512 ? bq[i] : (i < 1024 ? bk[i - 512] : bv[i - 1024]);
}

// ---------------------------- bf16 MFMA GEMM ------------------------------------
// C[M][N] = A[M][K] @ Bt[N][K]^T + bias. BMxBN tile, BK=32, 4 waves, wave owns
// WMxWN via (WM/16)x(WN/16) frags of 16x16x32 MFMA. m97-style linear staging.
template<int BM, int BN, int WM, int WN, int EPI>
__global__ __launch_bounds__(256) void gemm_kernel(
    const u16* __restrict__ A, const u16* __restrict__ Bt,
    const float* __restrict__ bias, void* __restrict__ out,
    int M, int N, int K) {
  constexpr int NWN = BN / WN;        // waves along N
  constexpr int MI = WM / 16, NI = WN / 16;
  __shared__ u16 As[BM * 32];
  __shared__ u16 Bs[BN * 32];
  const int tid = threadIdx.x;
  const int lane = tid & 63;
  const int wave = tid >> 6;
  const int m0 = blockIdx.y * BM;
  const int n0 = blockIdx.x * BN;
  const int wm = wave / NWN, wn = wave % NWN;
  const int g = lane >> 4, lr = lane & 15;
  const int srow = lane >> 2, scol = (lane & 3) * 8;

  f32x4 acc[MI][NI] = {};

  for (int k0 = 0; k0 < K; k0 += 32) {
#pragma unroll
    for (int ch = wave; ch < BM / 16; ch += 4)
      gload_lds16(A + (size_t)(m0 + ch * 16 + srow) * K + k0 + scol, &As[ch * 512]);
#pragma unroll
    for (int ch = wave; ch < BN / 16; ch += 4)
      gload_lds16(Bt + (size_t)(n0 + ch * 16 + srow) * K + k0 + scol, &Bs[ch * 512]);
    __syncthreads();
    bf16x8 a[MI], b[NI];
#pragma unroll
    for (int mi = 0; mi < MI; ++mi) a[mi] = *(const bf16x8*)&As[(wm * WM + mi * 16 + lr) * 32 + g * 8];
#pragma unroll
    for (int ni = 0; ni < NI; ++ni) b[ni] = *(const bf16x8*)&Bs[(wn * WN + ni * 16 + lr) * 32 + g * 8];
#pragma unroll
    for (int mi = 0; mi < MI; ++mi)
#pragma unroll
      for (int ni = 0; ni < NI; ++ni)
        acc[mi][ni] = __builtin_amdgcn_mfma_f32_16x16x32_bf16(a[mi], b[ni], acc[mi][ni], 0, 0, 0);
    __syncthreads();
  }

  // epilogue: D layout col=lane&15, row=(lane>>4)*4+reg  [m89-verified]
#pragma unroll
  for (int mi = 0; mi < MI; ++mi) {
#pragma unroll
    for (int ni = 0; ni < NI; ++ni) {
      const int col = n0 + wn * WN + ni * 16 + lr;
      const float bv = bias[col];
      f32x4 v = acc[mi][ni];
#pragma unroll
      for (int r = 0; r < 4; ++r) {
        const int row = m0 + wm * WM + mi * 16 + g * 4 + r;
        const float y = v[r] + bv;
        if (EPI == EPI_F32) {
          ((float*)out)[(size_t)row * N + col] = y;
        } else if (EPI == EPI_BF16_RELU) {
          ((u16*)out)[(size_t)row * N + col] = f2bf(fmaxf(y, 0.f));
        } else {  // EPI_QKV: out base = Qb; Kb = +4194304, Vtb = +8388608 elems
          u16* qb = (u16*)out;
          const int sec = col >> 9, cs = col & 511;
          const int b = row >> 10, t = row & 1023, h = cs >> 6, d = cs & 63;
          if (sec == 0)
            qb[((size_t)((b * 8 + h) * 1024 + t)) * 64 + d] = f2bf(y * QSCALE);
          else if (sec == 1)
            qb[4194304 + ((size_t)((b * 8 + h) * 1024 + t)) * 64 + d] = f2bf(y);
          else
            qb[8388608 + ((size_t)((b * 8 + h) * 64 + d)) * 1024 + t] = f2bf(y);
        }
      }
    }
  }
}

// ------------------- flash attention v3: KVBLK=64, swapped QK^T -----------------
// grid: 64 bh x 8 q-blocks(128 rows); 4 waves/block, wave owns 32 q rows.
// Per 64-key iter: 2 independent QK chains (32x32x16), one softmax over 32
// in-register scores (exp2 domain), T13 defer-rescale, 8 PV MFMA. Next-tile K
// prefetched a full iteration ahead; V loaded at iter top (~400cyc before use).
__global__ __launch_bounds__(256, 2) void attn3_kernel(
    const u16* __restrict__ Q, const u16* __restrict__ K,
    const u16* __restrict__ Vt, u16* __restrict__ ctx) {
  __shared__ u16 tl[4 * 2048];
  const int tid = threadIdx.x, lane = tid & 63, w = tid >> 6;
  const int bh = blockIdx.x >> 3, qb = blockIdx.x & 7;
  const int c = lane & 31, g = lane >> 5;
  const int q0 = qb * 128 + w * 32;

  // Q fragments (B-operand): col=c -> row q0+c, kk = 16s + 8g + j
  const u16* Qp = Q + ((size_t)bh * 1024 + q0 + c) * 64 + g * 8;
  const bf16x8 qf0 = *(const bf16x8*)(Qp);
  const bf16x8 qf1 = *(const bf16x8*)(Qp + 16);
  const bf16x8 qf2 = *(const bf16x8*)(Qp + 32);
  const bf16x8 qf3 = *(const bf16x8*)(Qp + 48);

  const u16* Kbase = K + (size_t)bh * 65536;
  const u16* Vbase = Vt + (size_t)bh * 65536;

  f32x16 cacc[2] = {};
  float mrun = -1e30f, lrun = 0.f;

  // preload K tile 0 (A-operand: row = key+c, kk = 16s+8g+j); sub-tiles @0,@32
  const u16* Kp0 = Kbase + (size_t)c * 64 + g * 8;
  bf16x8 kf0 = *(const bf16x8*)(Kp0);
  bf16x8 kf1 = *(const bf16x8*)(Kp0 + 16);
  bf16x8 kf2 = *(const bf16x8*)(Kp0 + 32);
  bf16x8 kf3 = *(const bf16x8*)(Kp0 + 48);
  bf16x8 kf4 = *(const bf16x8*)(Kp0 + 2048);
  bf16x8 kf5 = *(const bf16x8*)(Kp0 + 2048 + 16);
  bf16x8 kf6 = *(const bf16x8*)(Kp0 + 2048 + 32);
  bf16x8 kf7 = *(const bf16x8*)(Kp0 + 2048 + 48);

  for (int kt = 0; kt < 16; ++kt) {
    const int key0 = kt * 64;
    const int keyn = ((kt + 1) & 15) * 64;
    // current V frags (A-operand of PV: row d = 32*h2+c, kk along keys)
    const u16* Vp = Vbase + (size_t)c * 1024 + key0 + g * 8;
    const bf16x8 va00 = *(const bf16x8*)(Vp);
    const bf16x8 va01 = *(const bf16x8*)(Vp + 16);
    const bf16x8 va10 = *(const bf16x8*)(Vp + 32768);
    const bf16x8 va11 = *(const bf16x8*)(Vp + 32768 + 16);
    const bf16x8 vb00 = *(const bf16x8*)(Vp + 32);
    const bf16x8 vb01 = *(const bf16x8*)(Vp + 48);
    const bf16x8 vb10 = *(const bf16x8*)(Vp + 32768 + 32);
    const bf16x8 vb11 = *(const bf16x8*)(Vp + 32768 + 48);
    // prefetch next K tile (used next iteration)
    const u16* Kpn = Kbase + (size_t)(keyn + c) * 64 + g * 8;
    const bf16x8 n0 = *(const bf16x8*)(Kpn);
    const bf16x8 n1 = *(const bf16x8*)(Kpn + 16);
    const bf16x8 n2 = *(const bf16x8*)(Kpn + 32);
    const bf16x8 n3 = *(const bf16x8*)(Kpn + 48);
    const bf16x8 n4 = *(const bf16x8*)(Kpn + 2048);
    const bf16x8 n5 = *(const bf16x8*)(Kpn + 2048 + 16);
    const bf16x8 n6 = *(const bf16x8*)(Kpn + 2048 + 32);
    const bf16x8 n7 = *(const bf16x8*)(Kpn + 2048 + 48);

    // QK^T (swapped), two independent chains: S'[key][q] in log2 domain
    f32x16 sa = {}, sb = {};
    sa = __builtin_amdgcn_mfma_f32_32x32x16_bf16(kf0, qf0, sa, 0, 0, 0);
    sb = __builtin_amdgcn_mfma_f32_32x32x16_bf16(kf4, qf0, sb, 0, 0, 0);
    sa = __builtin_amdgcn_mfma_f32_32x32x16_bf16(kf1, qf1, sa, 0, 0, 0);
    sb = __builtin_amdgcn_mfma_f32_32x32x16_bf16(kf5, qf1, sb, 0, 0, 0);
    sa = __builtin_amdgcn_mfma_f32_32x32x16_bf16(kf2, qf2, sa, 0, 0, 0);
    sb = __builtin_amdgcn_mfma_f32_32x32x16_bf16(kf6, qf2, sb, 0, 0, 0);
    sa = __builtin_amdgcn_mfma_f32_32x32x16_bf16(kf3, qf3, sa, 0, 0, 0);
    sb = __builtin_amdgcn_mfma_f32_32x32x16_bf16(kf7, qf3, sb, 0, 0, 0);

    // online softmax over 32 scores (tree depth 5)
    float tm[16];
#pragma unroll
    for (int r = 0; r < 16; ++r) tm[r] = fmaxf(sa[r], sb[r]);
#pragma unroll
    for (int st = 8; st >= 1; st >>= 1)
#pragma unroll
      for (int r = 0; r < st; ++r) tm[r] = fmaxf(tm[r], tm[r + st]);
    const float mt = fmaxf(tm[0], __shfl_xor(tm[0], 32));
    // T13: skip rescale when running max didn't grow anywhere in the wave
    if (!__all(mt <= mrun)) {
      const float mnew = fmaxf(mrun, mt);
      const float al = fexp2(mrun - mnew);
#pragma unroll
      for (int r = 0; r < 16; ++r) { cacc[0][r] *= al; cacc[1][r] *= al; }
      lrun *= al;
      mrun = mnew;
    }
    float pa[16], pb[16];
#pragma unroll
    for (int r = 0; r < 16; ++r) pa[r] = fexp2(sa[r] - mrun);
#pragma unroll
    for (int r = 0; r < 16; ++r) pb[r] = fexp2(sb[r] - mrun);
    float ts[16];
#pragma unroll
    for (int r = 0; r < 16; ++r) ts[r] = pa[r] + pb[r];
#pragma unroll
    for (int st = 8; st >= 1; st >>= 1)
#pragma unroll
      for (int r = 0; r < st; ++r) ts[r] += ts[r + st];
    lrun += ts[0] + __shfl_xor(ts[0], 32);

    // pack P -> bf16 B-fragments (per sub-tile), partner exchange across g
    uint32_t wda[8], pwa[8], wdb[8], pwb[8];
#pragma unroll
    for (int i = 0; i < 8; ++i) wda[i] = cvt_pk_bf16(pa[2 * i], pa[2 * i + 1]);
#pragma unroll
    for (int i = 0; i < 8; ++i) wdb[i] = cvt_pk_bf16(pb[2 * i], pb[2 * i + 1]);
#pragma unroll
    for (int i = 0; i < 8; ++i) pwa[i] = __shfl_xor((int)wda[i], 32);
#pragma unroll
    for (int i = 0; i < 8; ++i) pwb[i] = __shfl_xor((int)wdb[i], 32);
    union { uint32_t u[4]; bf16x8 v; } b0a, b1a, b0b, b1b;
    const bool glo = (g == 0);
    b0a.u[0] = glo ? wda[0] : pwa[2]; b0a.u[1] = glo ? wda[1] : pwa[3];
    b0a.u[2] = glo ? pwa[0] : wda[2]; b0a.u[3] = glo ? pwa[1] : wda[3];
    b1a.u[0] = glo ? wda[4] : pwa[6]; b1a.u[1] = glo ? wda[5] : pwa[7];
    b1a.u[2] = glo ? pwa[4] : wda[6]; b1a.u[3] = glo ? pwa[5] : wda[7];
    b0b.u[0] = glo ? wdb[0] : pwb[2]; b0b.u[1] = glo ? wdb[1] : pwb[3];
    b0b.u[2] = glo ? pwb[0] : wdb[2]; b0b.u[3] = glo ? pwb[1] : wdb[3];
    b1b.u[0] = glo ? wdb[4] : pwb[6]; b1b.u[1] = glo ? wdb[5] : pwb[7];
    b1b.u[2] = glo ? pwb[4] : wdb[6]; b1b.u[3] = glo ? pwb[5] : wdb[7];

    // PV: ctx^T[d][q] accumulate, both sub-tiles
    cacc[0] = __builtin_amdgcn_mfma_f32_32x32x16_bf16(va00, b0a.v, cacc[0], 0, 0, 0);
    cacc[1] = __builtin_amdgcn_mfma_f32_32x32x16_bf16(va10, b0a.v, cacc[1], 0, 0, 0);
    cacc[0] = __builtin_amdgcn_mfma_f32_32x32x16_bf16(va01, b1a.v, cacc[0], 0, 0, 0);
    cacc[1] = __builtin_amdgcn_mfma_f32_32x32x16_bf16(va11, b1a.v, cacc[1], 0, 0, 0);
    cacc[0] = __builtin_amdgcn_mfma_f32_32x32x16_bf16(vb00, b0b.v, cacc[0], 0, 0, 0);
    cacc[1] = __builtin_amdgcn_mfma_f32_32x32x16_bf16(vb10, b0b.v, cacc[1], 0, 0, 0);
    cacc[0] = __builtin_amdgcn_mfma_f32_32x32x16_bf16(vb01, b1b.v, cacc[0], 0, 0, 0);
    cacc[1] = __builtin_amdgcn_mfma_f32_32x32x16_bf16(vb11, b1b.v, cacc[1], 0, 0, 0);

    kf0 = n0; kf1 = n1; kf2 = n2; kf3 = n3;
    kf4 = n4; kf5 = n5; kf6 = n6; kf7 = n7;
  }

  // epilogue: normalize, transpose via chunk-XOR-swizzled LDS, coalesced store
  const float inv = 1.0f / lrun;
  u16* tw = &tl[w * 2048];
#pragma unroll
  for (int h2 = 0; h2 < 2; ++h2) {
#pragma unroll
    for (int rq = 0; rq < 4; ++rq) {
      const u16 x0 = f2bf(cacc[h2][4 * rq + 0] * inv);
      const u16 x1 = f2bf(cacc[h2][4 * rq + 1] * inv);
      const u16 x2 = f2bf(cacc[h2][4 * rq + 2] * inv);
      const u16 x3 = f2bf(cacc[h2][4 * rq + 3] * inv);
      uint2 val;
      val.x = (uint32_t)x0 | ((uint32_t)x1 << 16);
      val.y = (uint32_t)x2 | ((uint32_t)x3 << 16);
      const int chunk = h2 * 4 + rq;  // d = chunk*8 + 4g + e
      *(uint2*)&tw[c * 64 + ((chunk ^ (c & 7)) * 8) + 4 * g] = val;
    }
  }
  __syncthreads();
  const int b_ = bh >> 3, h_ = bh & 7;
#pragma unroll
  for (int t = 0; t < 4; ++t) {
    const int lcg = t * 256 + tid;
    const int wv = lcg >> 8, rem = lcg & 255;
    const int q = rem >> 3, cg = rem & 7;
    const uint4 val = *(const uint4*)&tl[wv * 2048 + q * 64 + ((cg ^ (q & 7)) * 8)];
    const int grow = qb * 128 + wv * 32 + q;
    *(uint4*)&ctx[((size_t)(b_ * 1024 + grow)) * 512 + h_ * 64 + cg * 8] = val;
  }
}

// ----------------- residual + layernorm (1 wave per 512-col row) ----------------
__global__ __launch_bounds__(256) void ln_kernel(
    const float* __restrict__ A, const float* __restrict__ R,
    const float* __restrict__ gw, const float* __restrict__ bw,
    float* __restrict__ outF, u16* __restrict__ outB) {
  const int lane = threadIdx.x & 63, wave = threadIdx.x >> 6;
  const int row = blockIdx.x * 4 + wave;
  const float4* a4 = (const float4*)(A + (size_t)row * 512);
  const float4* r4 = (const float4*)(R + (size_t)row * 512);
  float4 x0 = a4[lane * 2], x1 = a4[lane * 2 + 1];
  float4 y0 = r4[lane * 2], y1 = r4[lane * 2 + 1];
  float v[8] = {x0.x + y0.x, x0.y + y0.y, x0.z + y0.z, x0.w + y0.w,
                x1.x + y1.x, x1.y + y1.y, x1.z + y1.z, x1.w + y1.w};
  float s = 0.f;
#pragma unroll
  for (int j = 0; j < 8; ++j) s += v[j];
#pragma unroll
  for (int off = 32; off >= 1; off >>= 1) s += __shfl_xor(s, off);
  const float mu = s * (1.f / 512.f);
  float vs = 0.f;
#pragma unroll
  for (int j = 0; j < 8; ++j) { const float d = v[j] - mu; vs += d * d; }
#pragma unroll
  for (int off = 32; off >= 1; off >>= 1) vs += __shfl_xor(vs, off);
  const float rstd = rsqrtf(vs * (1.f / 512.f) + 1e-5f);
  float4 gA = ((const float4*)gw)[lane * 2], gB = ((const float4*)gw)[lane * 2 + 1];
  float4 bA = ((const float4*)bw)[lane * 2], bB = ((const float4*)bw)[lane * 2 + 1];
  const float og[8] = {gA.x, gA.y, gA.z, gA.w, gB.x, gB.y, gB.z, gB.w};
  const float ob[8] = {bA.x, bA.y, bA.z, bA.w, bB.x, bB.y, bB.z, bB.w};
  float o[8];
#pragma unroll
  for (int j = 0; j < 8; ++j) o[j] = (v[j] - mu) * rstd * og[j] + ob[j];
  float4 w0 = {o[0], o[1], o[2], o[3]}, w1 = {o[4], o[5], o[6], o[7]};
  ((float4*)(outF + (size_t)row * 512))[lane * 2] = w0;
  ((float4*)(outF + (size_t)row * 512))[lane * 2 + 1] = w1;
  if (outB) {
    union { u16 u[8]; uint4 q; } pk;
#pragma unroll
    for (int j = 0; j < 8; ++j) pk.u[j] = f2bf(o[j]);
    ((uint4*)(outB + (size_t)row * 512))[lane] = pk.q;
  }
}

// --------------------------------- launch ---------------------------------------
extern "C" void kernel_launch(void* const* d_in, const int* in_sizes, int n_in,
                              void* d_out, int out_size, void* d_ws, size_t ws_size,
                              hipStream_t stream) {
  const float* x   = (const float*)d_in[0];
  const float* Wq  = (const float*)d_in[1];
  const float* bq  = (const float*)d_in[2];
  const float* Wk  = (const float*)d_in[3];
  const float* bk  = (const float*)d_in[4];
  const float* Wv  = (const float*)d_in[5];
  const float* bv  = (const float*)d_in[6];
  const float* Wo  = (const float*)d_in[7];
  const float* bo  = (const float*)d_in[8];
  const float* g1  = (const float*)d_in[9];
  const float* b1  = (const float*)d_in[10];
  const float* g2  = (const float*)d_in[11];
  const float* b2  = (const float*)d_in[12];
  const float* W1  = (const float*)d_in[13];
  const float* bf1 = (const float*)d_in[14];
  const float* W2  = (const float*)d_in[15];
  const float* bf2 = (const float*)d_in[16];

  char* ws = (char*)d_ws;
  u16*   xb      = (u16*)(ws + 0);           //  8192x512  bf16  (8.39 MB)
  u16*   Wqkvt   = (u16*)(ws + 8388608);     //  [1536][512] bf16 (Wq|Wk|Wv rows)
  u16*   Wot     = (u16*)(ws + 9961472);
  u16*   W1t     = (u16*)(ws + 10485760);    //  [2048][512]
  u16*   W2t     = (u16*)(ws + 12582912);    //  [512][2048]
  u16*   Qb      = (u16*)(ws + 14680064);    //  [BH][1024][64]  (Kb,Vtb follow)
  u16*   ctx     = (u16*)(ws + 39845888);    //  [8192][512] bf16
  float* attnout = (float*)(ws + 48234496);  //  [8192][512] f32
  float* bqkv    = (float*)(ws + 48234496);  //  1536 f32, dead before Wo GEMM
  float* h1f     = (float*)(ws + 65011712);  //  [8192][512] f32
  u16*   h1b     = (u16*)(ws + 81788928);    //  [8192][512] bf16
  u16*   mid     = (u16*)(ws + 31457280);    //  [8192][2048] bf16 (aliases Vtb/ctx/attnout, dead by then)

  // convert inputs to bf16 (weights transposed to [N][K]; QKV contiguous)
  cvt_kernel<<<2048, 256, 0, stream>>>(x, xb, 524288);
  tcvt_kernel<<<dim3(16, 16), 256, 0, stream>>>(Wq, Wqkvt, 512, 512);
  tcvt_kernel<<<dim3(16, 16), 256, 0, stream>>>(Wk, Wqkvt + 262144, 512, 512);
  tcvt_kernel<<<dim3(16, 16), 256, 0, stream>>>(Wv, Wqkvt + 524288, 512, 512);
  tcvt_kernel<<<dim3(16, 16), 256, 0, stream>>>(Wo, Wot, 512, 512);
  tcvt_kernel<<<dim3(64, 16), 256, 0, stream>>>(W1, W1t, 512, 2048);
  tcvt_kernel<<<dim3(16, 64), 256, 0, stream>>>(W2, W2t, 2048, 512);
  packb_kernel<<<6, 256, 0, stream>>>(bq, bk, bv, bqkv);

  // fused QKV projection (Q pre-scaled by 1/sqrt(D)*log2e)
  gemm_kernel<128, 128, 64, 64, EPI_QKV><<<dim3(12, 64), 256, 0, stream>>>(
      xb, Wqkvt, bqkv, Qb, 8192, 1536, 512);

  attn3_kernel<<<512, 256, 0, stream>>>(Qb, Qb + 4194304, Qb + 8388608, ctx);

  gemm_kernel<64, 128, 64, 32, EPI_F32><<<dim3(4, 128), 256, 0, stream>>>(
      ctx, Wot, bo, attnout, 8192, 512, 512);
  ln_kernel<<<2048, 256, 0, stream>>>(x, attnout, g1, b1, h1f, h1b);

  gemm_kernel<128, 128, 64, 64, EPI_BF16_RELU><<<dim3(16, 64), 256, 0, stream>>>(
      h1b, W1t, bf1, mid, 8192, 2048, 512);
  gemm_kernel<64, 128, 64, 32, EPI_F32><<<dim3(4, 128), 256, 0, stream>>>(
      mid, W2t, bf2, (float*)d_out, 8192, 512, 2048);
  ln_kernel<<<2048, 256, 0, stream>>>(h1f, (const float*)d_out, g2, b2, (float*)d_out, nullptr);
}

// Round 5
// 270.191 us; speedup vs baseline: 1.4535x; 1.1843x over previous
//
#include <hip/hip_runtime.h>
#include <cstdint>
#include <cstddef>

typedef unsigned short u16;
typedef __attribute__((ext_vector_type(8))) short bf16x8;
typedef __attribute__((ext_vector_type(4))) float f32x4;
typedef __attribute__((ext_vector_type(16))) float f32x16;

#define EPI_F32 0
#define EPI_BF16_RELU 1
#define EPI_QKV 2
#define EPI_PART 3

// 1/sqrt(64) * log2(e): QK^T scores come out in log2 domain -> exp2 softmax
#define QSCALE 0.18033688011112042f

__device__ __forceinline__ u16 f2bf(float f) {
  uint32_t u = __float_as_uint(f);
  return (u16)((u + 0x7FFFu + ((u >> 16) & 1u)) >> 16);
}

__device__ __forceinline__ uint32_t cvt_pk_bf16(float lo, float hi) {
  uint32_t r;
  asm("v_cvt_pk_bf16_f32 %0, %1, %2" : "=v"(r) : "v"(lo), "v"(hi));
  return r;
}

__device__ __forceinline__ float fexp2(float x) { return __builtin_amdgcn_exp2f(x); }

__device__ __forceinline__ void gload_lds16(const void* g, void* l) {
  __builtin_amdgcn_global_load_lds((const __attribute__((address_space(1))) void*)g,
                                   (__attribute__((address_space(3))) void*)l, 16, 0, 0);
}

// ---------------- fp32 -> bf16 convert (vectorized, 8 elems/thread) -------------
__global__ __launch_bounds__(256) void cvt_kernel(const float* __restrict__ in,
                                                  u16* __restrict__ out, int n8) {
  const int i = blockIdx.x * 256 + threadIdx.x;
  if (i >= n8) return;
  const float4* p = (const float4*)in + (size_t)i * 2;
  float4 a = p[0], b = p[1];
  union { u16 u[8]; uint4 q; } pk;
  pk.u[0] = f2bf(a.x); pk.u[1] = f2bf(a.y); pk.u[2] = f2bf(a.z); pk.u[3] = f2bf(a.w);
  pk.u[4] = f2bf(b.x); pk.u[5] = f2bf(b.y); pk.u[6] = f2bf(b.z); pk.u[7] = f2bf(b.w);
  ((uint4*)out)[i] = pk.q;
}

// ------------- fp32 W[K][N] -> bf16 Wt[N][K] (LDS-tiled transpose) --------------
__global__ __launch_bounds__(256) void tcvt_kernel(const float* __restrict__ W,
                                                   u16* __restrict__ Wt, int K, int N) {
  __shared__ float tl[32][33];
  const int t = threadIdx.x;
  const int kr0 = blockIdx.y * 32, nc0 = blockIdx.x * 32;
  const int r = t >> 3, cq = (t & 7) * 4;
  float4 v = *(const float4*)&W[(size_t)(kr0 + r) * N + nc0 + cq];
  tl[r][cq + 0] = v.x; tl[r][cq + 1] = v.y; tl[r][cq + 2] = v.z; tl[r][cq + 3] = v.w;
  __syncthreads();
  union { u16 u[4]; uint2 q; } pk;
#pragma unroll
  for (int j = 0; j < 4; ++j) pk.u[j] = f2bf(tl[cq + j][r]);
  *(uint2*)&Wt[(size_t)(nc0 + r) * K + kr0 + cq] = pk.q;
}

// ---- fused transpose of the four 512x512 weights (z selects Wq/Wk/Wv/Wo) -------
__global__ __launch_bounds__(256) void tcvt4_kernel(
    const float* __restrict__ Wq, const float* __restrict__ Wk,
    const float* __restrict__ Wv, const float* __restrict__ Wo,
    u16* __restrict__ outQKV, u16* __restrict__ outO) {
  __shared__ float tl[32][33];
  const int z = blockIdx.z;
  const float* W = z == 0 ? Wq : (z == 1 ? Wk : (z == 2 ? Wv : Wo));
  u16* Wt = z < 3 ? outQKV + z * 262144 : outO;
  const int t = threadIdx.x;
  const int kr0 = blockIdx.y * 32, nc0 = blockIdx.x * 32;
  const int r = t >> 3, cq = (t & 7) * 4;
  float4 v = *(const float4*)&W[(size_t)(kr0 + r) * 512 + nc0 + cq];
  tl[r][cq + 0] = v.x; tl[r][cq + 1] = v.y; tl[r][cq + 2] = v.z; tl[r][cq + 3] = v.w;
  __syncthreads();
  union { u16 u[4]; uint2 q; } pk;
#pragma unroll
  for (int j = 0; j < 4; ++j) pk.u[j] = f2bf(tl[cq + j][r]);
  *(uint2*)&Wt[(size_t)(nc0 + r) * 512 + kr0 + cq] = pk.q;
}

// ---------------- pack bq|bk|bv into one contiguous 1536-float bias -------------
__global__ __launch_bounds__(256) void packb_kernel(const float* __restrict__ bq,
                                                    const float* __restrict__ bk,
                                                    const float* __restrict__ bv,
                                                    float* __restrict__ out) {
  const int i = blockIdx.x * 256 + threadIdx.x;
  if (i >= 1536) return;
  out[i] = i < 512 ? bq[i] : (i < 1024 ? bk[i - 512] : bv[i - 1024]);
}

// ---------------------------- bf16 MFMA GEMM ------------------------------------
// C[M][N] = A[M][K] @ Bt[N][K]^T (+ bias). BMxBN tile, BK=32, 4 waves. SPLIT>1:
// blockIdx.z handles K-range slice, EPI_PART writes f32 partial to out+z*M*N.
template<int BM, int BN, int WM, int WN, int EPI, int SPLIT>
__global__ __launch_bounds__(256) void gemm_kernel(
    const u16* __restrict__ A, const u16* __restrict__ Bt,
    const float* __restrict__ bias, void* __restrict__ out,
    int M, int N, int K) {
  constexpr int NWN = BN / WN;        // waves along N
  constexpr int MI = WM / 16, NI = WN / 16;
  __shared__ u16 As[BM * 32];
  __shared__ u16 Bs[BN * 32];
  const int tid = threadIdx.x;
  const int lane = tid & 63;
  const int wave = tid >> 6;
  const int m0 = blockIdx.y * BM;
  const int n0 = blockIdx.x * BN;
  const int wm = wave / NWN, wn = wave % NWN;
  const int g = lane >> 4, lr = lane & 15;
  const int srow = lane >> 2, scol = (lane & 3) * 8;

  f32x4 acc[MI][NI] = {};

  const int kBeg = (SPLIT > 1) ? blockIdx.z * (K / SPLIT) : 0;
  const int kEnd = (SPLIT > 1) ? kBeg + (K / SPLIT) : K;
  for (int k0 = kBeg; k0 < kEnd; k0 += 32) {
#pragma unroll
    for (int ch = wave; ch < BM / 16; ch += 4)
      gload_lds16(A + (size_t)(m0 + ch * 16 + srow) * K + k0 + scol, &As[ch * 512]);
#pragma unroll
    for (int ch = wave; ch < BN / 16; ch += 4)
      gload_lds16(Bt + (size_t)(n0 + ch * 16 + srow) * K + k0 + scol, &Bs[ch * 512]);
    __syncthreads();
    bf16x8 a[MI], b[NI];
#pragma unroll
    for (int mi = 0; mi < MI; ++mi) a[mi] = *(const bf16x8*)&As[(wm * WM + mi * 16 + lr) * 32 + g * 8];
#pragma unroll
    for (int ni = 0; ni < NI; ++ni) b[ni] = *(const bf16x8*)&Bs[(wn * WN + ni * 16 + lr) * 32 + g * 8];
#pragma unroll
    for (int mi = 0; mi < MI; ++mi)
#pragma unroll
      for (int ni = 0; ni < NI; ++ni)
        acc[mi][ni] = __builtin_amdgcn_mfma_f32_16x16x32_bf16(a[mi], b[ni], acc[mi][ni], 0, 0, 0);
    __syncthreads();
  }

  // epilogue: D layout col=lane&15, row=(lane>>4)*4+reg  [m89-verified]
#pragma unroll
  for (int mi = 0; mi < MI; ++mi) {
#pragma unroll
    for (int ni = 0; ni < NI; ++ni) {
      const int col = n0 + wn * WN + ni * 16 + lr;
      const float bv = (EPI == EPI_PART) ? 0.f : bias[col];
      f32x4 v = acc[mi][ni];
#pragma unroll
      for (int r = 0; r < 4; ++r) {
        const int row = m0 + wm * WM + mi * 16 + g * 4 + r;
        const float y = v[r] + bv;
        if (EPI == EPI_F32) {
          ((float*)out)[(size_t)row * N + col] = y;
        } else if (EPI == EPI_PART) {
          ((float*)out)[(size_t)blockIdx.z * M * N + (size_t)row * N + col] = y;
        } else if (EPI == EPI_BF16_RELU) {
          ((u16*)out)[(size_t)row * N + col] = f2bf(fmaxf(y, 0.f));
        } else {  // EPI_QKV: out base = Qb; Kb = +4194304, Vtb = +8388608 elems
          u16* qb = (u16*)out;
          const int sec = col >> 9, cs = col & 511;
          const int b = row >> 10, t = row & 1023, h = cs >> 6, d = cs & 63;
          if (sec == 0)
            qb[((size_t)((b * 8 + h) * 1024 + t)) * 64 + d] = f2bf(y * QSCALE);
          else if (sec == 1)
            qb[4194304 + ((size_t)((b * 8 + h) * 1024 + t)) * 64 + d] = f2bf(y);
          else
            qb[8388608 + ((size_t)((b * 8 + h) * 64 + d)) * 1024 + t] = f2bf(y);
        }
      }
    }
  }
}

// ------------- flash attention v4: LDS-staged K/V, double-buffered --------------
// grid: 64 bh x 8 q-blocks(128 rows); 4 waves, wave owns 32 q rows. Per 64-key
// tile: async global_load_lds stage of NEXT tile (linear LDS dest, inverse-
// swizzled global source), ds_read_b128 frags (XOR cg^(row&7) swizzle), 16 MFMA
// 32x32x16, in-register exp2 softmax with T13 defer-rescale. 1 barrier/tile.
__global__ __launch_bounds__(256, 2) void attn4_kernel(
    const u16* __restrict__ Q, const u16* __restrict__ K,
    const u16* __restrict__ Vt, u16* __restrict__ ctx) {
  __shared__ u16 smem[16384];  // [0:8192) K dbuf, [8192:16384) V dbuf; epi reuse
  const int tid = threadIdx.x, lane = tid & 63, w = tid >> 6;
  const int bh = blockIdx.x >> 3, qb = blockIdx.x & 7;
  const int c = lane & 31, g = lane >> 5;
  const int q0 = qb * 128 + w * 32;

  // Q fragments (B-operand): col=c -> row q0+c, kk = 16s + 8g + j
  const u16* Qp = Q + ((size_t)bh * 1024 + q0 + c) * 64 + g * 8;
  const bf16x8 qf0 = *(const bf16x8*)(Qp);
  const bf16x8 qf1 = *(const bf16x8*)(Qp + 16);
  const bf16x8 qf2 = *(const bf16x8*)(Qp + 32);
  const bf16x8 qf3 = *(const bf16x8*)(Qp + 48);

  const u16* Kbase = K + (size_t)bh * 65536;
  const u16* Vbase = Vt + (size_t)bh * 65536;

  // staging geometry: wave w covers rows w*16+i*8+(l>>3), col-slot l&7; the
  // global source col-group is slot^(row&7) so a linear LDS write equals the
  // swizzled layout read back below (rule 21: linear dest + pre-swz source).
  const int r0 = w * 16 + (lane >> 3), r1 = r0 + 8;
  const int cg0 = ((lane & 7) ^ (r0 & 7)) << 3;  // u16 offset within row
  const int cg1 = ((lane & 7) ^ (r1 & 7)) << 3;

#define STAGE(buf, key0) do {                                                       \
    gload_lds16(Kbase + (size_t)((key0) + r0) * 64 + cg0, &smem[(buf)*4096 + w*1024]);       \
    gload_lds16(Kbase + (size_t)((key0) + r1) * 64 + cg1, &smem[(buf)*4096 + w*1024 + 512]); \
    gload_lds16(Vbase + (size_t)r0 * 1024 + (key0) + cg0, &smem[8192 + (buf)*4096 + w*1024]);\
    gload_lds16(Vbase + (size_t)r1 * 1024 + (key0) + cg1, &smem[8192 + (buf)*4096 + w*1024 + 512]); \
  } while (0)

  // swizzled fragment read: row r, logical col-group cg -> slot cg^(r&7)
  const int cs = c & 7;
  const int ro0 = c * 64, ro1 = (32 + c) * 64;  // (32+c)&7 == c&7
#define KS(buf, ro, cg) (*(const bf16x8*)&smem[(buf)*4096 + (ro) + ((((cg)) ^ cs) << 3)])
#define VS(buf, ro, cg) (*(const bf16x8*)&smem[8192 + (buf)*4096 + (ro) + ((((cg)) ^ cs) << 3)])

  f32x16 cacc[2] = {};
  float mrun = -1e30f, lrun = 0.f;

  STAGE(0, 0);
  __syncthreads();

  for (int kt = 0; kt < 16; ++kt) {
    const int buf = kt & 1;
    if (kt < 15) STAGE(buf ^ 1, (kt + 1) * 64);

    // K frags: rows c / 32+c, cols kk = 16s + 8g + j -> cg = 2s + g
    const bf16x8 kf0 = KS(buf, ro0, g),     kf1 = KS(buf, ro0, 2 + g);
    const bf16x8 kf2 = KS(buf, ro0, 4 + g), kf3 = KS(buf, ro0, 6 + g);
    const bf16x8 kf4 = KS(buf, ro1, g),     kf5 = KS(buf, ro1, 2 + g);
    const bf16x8 kf6 = KS(buf, ro1, 4 + g), kf7 = KS(buf, ro1, 6 + g);

    // QK^T (swapped), two independent chains: S'[key][q] in log2 domain
    f32x16 sa = {}, sb = {};
    sa = __builtin_amdgcn_mfma_f32_32x32x16_bf16(kf0, qf0, sa, 0, 0, 0);
    sb = __builtin_amdgcn_mfma_f32_32x32x16_bf16(kf4, qf0, sb, 0, 0, 0);
    sa = __builtin_amdgcn_mfma_f32_32x32x16_bf16(kf1, qf1, sa, 0, 0, 0);
    sb = __builtin_amdgcn_mfma_f32_32x32x16_bf16(kf5, qf1, sb, 0, 0, 0);
    sa = __builtin_amdgcn_mfma_f32_32x32x16_bf16(kf2, qf2, sa, 0, 0, 0);
    sb = __builtin_amdgcn_mfma_f32_32x32x16_bf16(kf6, qf2, sb, 0, 0, 0);
    sa = __builtin_amdgcn_mfma_f32_32x32x16_bf16(kf3, qf3, sa, 0, 0, 0);
    sb = __builtin_amdgcn_mfma_f32_32x32x16_bf16(kf7, qf3, sb, 0, 0, 0);

    // online softmax over 32 scores (tree depth 5)
    float tm[16];
#pragma unroll
    for (int r = 0; r < 16; ++r) tm[r] = fmaxf(sa[r], sb[r]);
#pragma unroll
    for (int st = 8; st >= 1; st >>= 1)
#pragma unroll
      for (int r = 0; r < st; ++r) tm[r] = fmaxf(tm[r], tm[r + st]);
    const float mt = fmaxf(tm[0], __shfl_xor(tm[0], 32));
    // T13: skip rescale when running max didn't grow anywhere in the wave
    if (!__all(mt <= mrun)) {
      const float mnew = fmaxf(mrun, mt);
      const float al = fexp2(mrun - mnew);
#pragma unroll
      for (int r = 0; r < 16; ++r) { cacc[0][r] *= al; cacc[1][r] *= al; }
      lrun *= al;
      mrun = mnew;
    }
    float pa[16], pb[16];
#pragma unroll
    for (int r = 0; r < 16; ++r) pa[r] = fexp2(sa[r] - mrun);
#pragma unroll
    for (int r = 0; r < 16; ++r) pb[r] = fexp2(sb[r] - mrun);
    float ts[16];
#pragma unroll
    for (int r = 0; r < 16; ++r) ts[r] = pa[r] + pb[r];
#pragma unroll
    for (int st = 8; st >= 1; st >>= 1)
#pragma unroll
      for (int r = 0; r < st; ++r) ts[r] += ts[r + st];
    lrun += ts[0] + __shfl_xor(ts[0], 32);

    // pack P -> bf16 B-fragments (per sub-tile), partner exchange across g
    uint32_t wda[8], pwa[8], wdb[8], pwb[8];
#pragma unroll
    for (int i = 0; i < 8; ++i) wda[i] = cvt_pk_bf16(pa[2 * i], pa[2 * i + 1]);
#pragma unroll
    for (int i = 0; i < 8; ++i) wdb[i] = cvt_pk_bf16(pb[2 * i], pb[2 * i + 1]);
#pragma unroll
    for (int i = 0; i < 8; ++i) pwa[i] = __shfl_xor((int)wda[i], 32);
#pragma unroll
    for (int i = 0; i < 8; ++i) pwb[i] = __shfl_xor((int)wdb[i], 32);
    union { uint32_t u[4]; bf16x8 v; } b0a, b1a, b0b, b1b;
    const bool glo = (g == 0);
    b0a.u[0] = glo ? wda[0] : pwa[2]; b0a.u[1] = glo ? wda[1] : pwa[3];
    b0a.u[2] = glo ? pwa[0] : wda[2]; b0a.u[3] = glo ? pwa[1] : wda[3];
    b1a.u[0] = glo ? wda[4] : pwa[6]; b1a.u[1] = glo ? wda[5] : pwa[7];
    b1a.u[2] = glo ? pwa[4] : wda[6]; b1a.u[3] = glo ? pwa[5] : wda[7];
    b0b.u[0] = glo ? wdb[0] : pwb[2]; b0b.u[1] = glo ? wdb[1] : pwb[3];
    b0b.u[2] = glo ? pwb[0] : wdb[2]; b0b.u[3] = glo ? pwb[1] : wdb[3];
    b1b.u[0] = glo ? wdb[4] : pwb[6]; b1b.u[1] = glo ? wdb[5] : pwb[7];
    b1b.u[2] = glo ? pwb[4] : wdb[6]; b1b.u[3] = glo ? pwb[5] : wdb[7];

    // V frags: rows d=c / 32+c, key-cols cg = {g,2+g,4+g,6+g}
    const bf16x8 va00 = VS(buf, ro0, g),     va01 = VS(buf, ro0, 2 + g);
    const bf16x8 vb00 = VS(buf, ro0, 4 + g), vb01 = VS(buf, ro0, 6 + g);
    const bf16x8 va10 = VS(buf, ro1, g),     va11 = VS(buf, ro1, 2 + g);
    const bf16x8 vb10 = VS(buf, ro1, 4 + g), vb11 = VS(buf, ro1, 6 + g);

    // PV: ctx^T[d][q] accumulate, both sub-tiles
    cacc[0] = __builtin_amdgcn_mfma_f32_32x32x16_bf16(va00, b0a.v, cacc[0], 0, 0, 0);
    cacc[1] = __builtin_amdgcn_mfma_f32_32x32x16_bf16(va10, b0a.v, cacc[1], 0, 0, 0);
    cacc[0] = __builtin_amdgcn_mfma_f32_32x32x16_bf16(va01, b1a.v, cacc[0], 0, 0, 0);
    cacc[1] = __builtin_amdgcn_mfma_f32_32x32x16_bf16(va11, b1a.v, cacc[1], 0, 0, 0);
    cacc[0] = __builtin_amdgcn_mfma_f32_32x32x16_bf16(vb00, b0b.v, cacc[0], 0, 0, 0);
    cacc[1] = __builtin_amdgcn_mfma_f32_32x32x16_bf16(vb10, b0b.v, cacc[1], 0, 0, 0);
    cacc[0] = __builtin_amdgcn_mfma_f32_32x32x16_bf16(vb01, b1b.v, cacc[0], 0, 0, 0);
    cacc[1] = __builtin_amdgcn_mfma_f32_32x32x16_bf16(vb11, b1b.v, cacc[1], 0, 0, 0);

    __syncthreads();  // staging of buf^1 complete; all reads of buf done
  }

  // epilogue: normalize, transpose via chunk-XOR-swizzled LDS, coalesced store
  const float inv = 1.0f / lrun;
  u16* tw = &smem[w * 2048];
#pragma unroll
  for (int h2 = 0; h2 < 2; ++h2) {
#pragma unroll
    for (int rq = 0; rq < 4; ++rq) {
      const u16 x0 = f2bf(cacc[h2][4 * rq + 0] * inv);
      const u16 x1 = f2bf(cacc[h2][4 * rq + 1] * inv);
      const u16 x2 = f2bf(cacc[h2][4 * rq + 2] * inv);
      const u16 x3 = f2bf(cacc[h2][4 * rq + 3] * inv);
      uint2 val;
      val.x = (uint32_t)x0 | ((uint32_t)x1 << 16);
      val.y = (uint32_t)x2 | ((uint32_t)x3 << 16);
      const int chunk = h2 * 4 + rq;  // d = chunk*8 + 4g + e
      *(uint2*)&tw[c * 64 + ((chunk ^ (c & 7)) * 8) + 4 * g] = val;
    }
  }
  __syncthreads();
  const int b_ = bh >> 3, h_ = bh & 7;
#pragma unroll
  for (int t = 0; t < 4; ++t) {
    const int lcg = t * 256 + tid;
    const int wv = lcg >> 8, rem = lcg & 255;
    const int q = rem >> 3, cg = rem & 7;
    const uint4 val = *(const uint4*)&smem[wv * 2048 + q * 64 + ((cg ^ (q & 7)) * 8)];
    const int grow = qb * 128 + wv * 32 + q;
    *(uint4*)&ctx[((size_t)(b_ * 1024 + grow)) * 512 + h_ * 64 + cg * 8] = val;
  }
#undef STAGE
#undef KS
#undef VS
}

// ------- residual + split-K-combine + layernorm (1 wave per 512-col row) --------
// v = A + P0 + P1 + pb;  out = LN(v)*g + b.  A is f32 or bf16 per template.
template<bool ABF16>
__global__ __launch_bounds__(256) void lnc_kernel(
    const void* __restrict__ Av, const float* __restrict__ P0,
    const float* __restrict__ P1, const float* __restrict__ pb,
    const float* __restrict__ gw, const float* __restrict__ bw,
    float* __restrict__ outF, u16* __restrict__ outB) {
  const int lane = threadIdx.x & 63, wave = threadIdx.x >> 6;
  const int row = blockIdx.x * 4 + wave;
  float a[8];
  if (ABF16) {
    const uint4 q = ((const uint4*)((const u16*)Av + (size_t)row * 512))[lane];
    const u16* pu = (const u16*)&q;
#pragma unroll
    for (int j = 0; j < 8; ++j) a[j] = __uint_as_float((uint32_t)pu[j] << 16);
  } else {
    const float4* a4 = (const float4*)((const float*)Av + (size_t)row * 512);
    const float4 x0 = a4[lane * 2], x1 = a4[lane * 2 + 1];
    a[0] = x0.x; a[1] = x0.y; a[2] = x0.z; a[3] = x0.w;
    a[4] = x1.x; a[5] = x1.y; a[6] = x1.z; a[7] = x1.w;
  }
  const float4* p04 = (const float4*)(P0 + (size_t)row * 512);
  const float4* p14 = (const float4*)(P1 + (size_t)row * 512);
  const float4 q00 = p04[lane * 2], q01 = p04[lane * 2 + 1];
  const float4 q10 = p14[lane * 2], q11 = p14[lane * 2 + 1];
  const float4 e0 = ((const float4*)pb)[lane * 2], e1 = ((const float4*)pb)[lane * 2 + 1];
  float v[8] = {a[0] + q00.x + q10.x + e0.x, a[1] + q00.y + q10.y + e0.y,
                a[2] + q00.z + q10.z + e0.z, a[3] + q00.w + q10.w + e0.w,
                a[4] + q01.x + q11.x + e1.x, a[5] + q01.y + q11.y + e1.y,
                a[6] + q01.z + q11.z + e1.z, a[7] + q01.w + q11.w + e1.w};
  float s = 0.f;
#pragma unroll
  for (int j = 0; j < 8; ++j) s += v[j];
#pragma unroll
  for (int off = 32; off >= 1; off >>= 1) s += __shfl_xor(s, off);
  const float mu = s * (1.f / 512.f);
  float vs = 0.f;
#pragma unroll
  for (int j = 0; j < 8; ++j) { const float d = v[j] - mu; vs += d * d; }
#pragma unroll
  for (int off = 32; off >= 1; off >>= 1) vs += __shfl_xor(vs, off);
  const float rstd = rsqrtf(vs * (1.f / 512.f) + 1e-5f);
  const float4 gA = ((const float4*)gw)[lane * 2], gB = ((const float4*)gw)[lane * 2 + 1];
  const float4 bA = ((const float4*)bw)[lane * 2], bB = ((const float4*)bw)[lane * 2 + 1];
  const float og[8] = {gA.x, gA.y, gA.z, gA.w, gB.x, gB.y, gB.z, gB.w};
  const float ob[8] = {bA.x, bA.y, bA.z, bA.w, bB.x, bB.y, bB.z, bB.w};
  float o[8];
#pragma unroll
  for (int j = 0; j < 8; ++j) o[j] = (v[j] - mu) * rstd * og[j] + ob[j];
  if (outF) {
    float4 w0 = {o[0], o[1], o[2], o[3]}, w1 = {o[4], o[5], o[6], o[7]};
    ((float4*)(outF + (size_t)row * 512))[lane * 2] = w0;
    ((float4*)(outF + (size_t)row * 512))[lane * 2 + 1] = w1;
  }
  if (outB) {
    union { u16 u[8]; uint4 q; } pk;
#pragma unroll
    for (int j = 0; j < 8; ++j) pk.u[j] = f2bf(o[j]);
    ((uint4*)(outB + (size_t)row * 512))[lane] = pk.q;
  }
}

// --------------------------------- launch ---------------------------------------
extern "C" void kernel_launch(void* const* d_in, const int* in_sizes, int n_in,
                              void* d_out, int out_size, void* d_ws, size_t ws_size,
                              hipStream_t stream) {
  const float* x   = (const float*)d_in[0];
  const float* Wq  = (const float*)d_in[1];
  const float* bq  = (const float*)d_in[2];
  const float* Wk  = (const float*)d_in[3];
  const float* bk  = (const float*)d_in[4];
  const float* Wv  = (const float*)d_in[5];
  const float* bv  = (const float*)d_in[6];
  const float* Wo  = (const float*)d_in[7];
  const float* bo  = (const float*)d_in[8];
  const float* g1  = (const float*)d_in[9];
  const float* b1  = (const float*)d_in[10];
  const float* g2  = (const float*)d_in[11];
  const float* b2  = (const float*)d_in[12];
  const float* W1  = (const float*)d_in[13];
  const float* bf1 = (const float*)d_in[14];
  const float* W2  = (const float*)d_in[15];
  const float* bf2 = (const float*)d_in[16];

  char* ws = (char*)d_ws;
  u16*   xb    = (u16*)(ws + 0);           // [8192][512] bf16
  u16*   Wqkvt = (u16*)(ws + 8388608);     // [1536][512] bf16
  u16*   Wot   = (u16*)(ws + 9961472);     // [512][512]
  u16*   W1t   = (u16*)(ws + 10485760);    // [2048][512]
  u16*   W2t   = (u16*)(ws + 12582912);    // [512][2048]
  u16*   Qb    = (u16*)(ws + 14680064);    // [BH][1024][64]; Kb,Vtb follow
  u16*   ctx   = (u16*)(ws + 39845888);    // [8192][512] bf16
  float* P0    = (float*)(ws + 48234496);  // [8192][512] f32 partial (P1 follows)
  u16*   h1b   = (u16*)(ws + 81788928);    // [8192][512] bf16
  u16*   mid   = (u16*)(ws + 14680064);    // [8192][2048] bf16 (over Qb..ctx, dead)
  float* bqkv  = (float*)(ws + 39845888);  // 1536 f32 (over ctx, dead before attn)

  cvt_kernel<<<2048, 256, 0, stream>>>(x, xb, 524288);
  tcvt4_kernel<<<dim3(16, 16, 4), 256, 0, stream>>>(Wq, Wk, Wv, Wo, Wqkvt, Wot);
  tcvt_kernel<<<dim3(64, 16), 256, 0, stream>>>(W1, W1t, 512, 2048);
  tcvt_kernel<<<dim3(16, 64), 256, 0, stream>>>(W2, W2t, 2048, 512);
  packb_kernel<<<6, 256, 0, stream>>>(bq, bk, bv, bqkv);

  // fused QKV projection (Q pre-scaled by 1/sqrt(D)*log2e)
  gemm_kernel<128, 128, 64, 64, EPI_QKV, 1><<<dim3(12, 64), 256, 0, stream>>>(
      xb, Wqkvt, bqkv, Qb, 8192, 1536, 512);

  attn4_kernel<<<512, 256, 0, stream>>>(Qb, Qb + 4194304, Qb + 8388608, ctx);

  // Wo: split-K x2 partials; LN1 combines x + P0 + P1 + bo -> h1b (bf16 only)
  gemm_kernel<64, 128, 64, 32, EPI_PART, 2><<<dim3(4, 128, 2), 256, 0, stream>>>(
      ctx, Wot, nullptr, P0, 8192, 512, 512);
  lnc_kernel<false><<<2048, 256, 0, stream>>>(x, P0, P0 + 4194304, bo, g1, b1,
                                              nullptr, h1b);

  gemm_kernel<128, 128, 64, 64, EPI_BF16_RELU, 1><<<dim3(16, 64), 256, 0, stream>>>(
      h1b, W1t, bf1, mid, 8192, 2048, 512);

  // FFN2: split-K x2 partials; LN2 combines h1b + P0 + P1 + bf2 -> d_out (f32)
  gemm_kernel<64, 128, 64, 32, EPI_PART, 2><<<dim3(4, 128, 2), 256, 0, stream>>>(
      mid, W2t, nullptr, P0, 8192, 512, 2048);
  lnc_kernel<true><<<2048, 256, 0, stream>>>(h1b, P0, P0 + 4194304, bf2, g2, b2,
                                             (float*)d_out, nullptr);
}

// Round 6
// 264.647 us; speedup vs baseline: 1.4840x; 1.0209x over previous
//
#include <hip/hip_runtime.h>
#include <cstdint>
#include <cstddef>

typedef unsigned short u16;
typedef __attribute__((ext_vector_type(8))) short bf16x8;
typedef __attribute__((ext_vector_type(4))) float f32x4;
typedef __attribute__((ext_vector_type(16))) float f32x16;

#define EPI_F32 0
#define EPI_BF16_RELU 1
#define EPI_QKV 2
#define EPI_PART 3

// 1/sqrt(64) * log2(e): QK^T scores come out in log2 domain -> exp2 softmax
#define QSCALE 0.18033688011112042f

__device__ __forceinline__ u16 f2bf(float f) {
  uint32_t u = __float_as_uint(f);
  return (u16)((u + 0x7FFFu + ((u >> 16) & 1u)) >> 16);
}

__device__ __forceinline__ uint32_t cvt_pk_bf16(float lo, float hi) {
  uint32_t r;
  asm("v_cvt_pk_bf16_f32 %0, %1, %2" : "=v"(r) : "v"(lo), "v"(hi));
  return r;
}

__device__ __forceinline__ float fexp2(float x) { return __builtin_amdgcn_exp2f(x); }

__device__ __forceinline__ void gload_lds16(const void* g, void* l) {
  __builtin_amdgcn_global_load_lds((const __attribute__((address_space(1))) void*)g,
                                   (__attribute__((address_space(3))) void*)l, 16, 0, 0);
}

// ------------------------------ fused prep kernel --------------------------------
// blocks [0,2048): x f32->bf16; [2048,3072): Wq/Wk/Wv/Wo transpose;
// [3072,4096): W1; [4096,5120): W2; [5120,5126): bias pack.
__device__ __forceinline__ void tcvt_tile(const float* __restrict__ W,
                                          u16* __restrict__ Wt, int K, int N,
                                          int bx, int by, float (*tl)[33], int t) {
  const int kr0 = by * 32, nc0 = bx * 32;
  const int r = t >> 3, cq = (t & 7) * 4;
  float4 v = *(const float4*)&W[(size_t)(kr0 + r) * N + nc0 + cq];
  tl[r][cq + 0] = v.x; tl[r][cq + 1] = v.y; tl[r][cq + 2] = v.z; tl[r][cq + 3] = v.w;
  __syncthreads();
  union { u16 u[4]; uint2 q; } pk;
#pragma unroll
  for (int j = 0; j < 4; ++j) pk.u[j] = f2bf(tl[cq + j][r]);
  *(uint2*)&Wt[(size_t)(nc0 + r) * K + kr0 + cq] = pk.q;
}

__global__ __launch_bounds__(256) void prep_kernel(
    const float* __restrict__ x, u16* __restrict__ xb,
    const float* __restrict__ Wq, const float* __restrict__ Wk,
    const float* __restrict__ Wv, const float* __restrict__ Wo,
    u16* __restrict__ Wqkvt, u16* __restrict__ Wot,
    const float* __restrict__ W1, u16* __restrict__ W1t,
    const float* __restrict__ W2, u16* __restrict__ W2t,
    const float* __restrict__ bq, const float* __restrict__ bk,
    const float* __restrict__ bv, float* __restrict__ bqkv) {
  __shared__ float tl[32][33];
  const int b = blockIdx.x, t = threadIdx.x;
  if (b < 2048) {
    const int i = b * 256 + t;  // < 524288 groups of 8
    const float4* p = (const float4*)x + (size_t)i * 2;
    float4 a = p[0], c = p[1];
    union { u16 u[8]; uint4 q; } pk;
    pk.u[0] = f2bf(a.x); pk.u[1] = f2bf(a.y); pk.u[2] = f2bf(a.z); pk.u[3] = f2bf(a.w);
    pk.u[4] = f2bf(c.x); pk.u[5] = f2bf(c.y); pk.u[6] = f2bf(c.z); pk.u[7] = f2bf(c.w);
    ((uint4*)xb)[i] = pk.q;
  } else if (b < 3072) {
    const int u = b - 2048, z = u >> 8, s = u & 255;
    const float* W = z == 0 ? Wq : (z == 1 ? Wk : (z == 2 ? Wv : Wo));
    u16* Wt = z < 3 ? Wqkvt + z * 262144 : Wot;
    tcvt_tile(W, Wt, 512, 512, s & 15, s >> 4, tl, t);
  } else if (b < 4096) {
    const int u = b - 3072;
    tcvt_tile(W1, W1t, 512, 2048, u % 64, u / 64, tl, t);
  } else if (b < 5120) {
    const int u = b - 4096;
    tcvt_tile(W2, W2t, 2048, 512, u % 16, u / 16, tl, t);
  } else {
    const int i = (b - 5120) * 256 + t;
    if (i < 1536) bqkv[i] = i < 512 ? bq[i] : (i < 1024 ? bk[i - 512] : bv[i - 1024]);
  }
}

// ------------------- pipelined bf16 GEMM (BK=64, dbuf, counted vmcnt) ------------
// C[M][N] = A[M][K] @ Bt[N][K]^T + bias. 128x128 tile, 4 waves (2x2), wave 64x64.
// Raw s_barrier + manual vmcnt(8): tile t+1's loads land while t+2's stay in
// flight -> staging latency spans barriers (T4). LDS slot^(row&7) swizzle via
// pre-swizzled global source (rule 21): b128 reads hit all 32 banks.
template<int BM, int BN, int WM, int WN, int EPI, int SPLIT>
__global__ __launch_bounds__(256, 2) void gemm2_kernel(
    const u16* __restrict__ A, const u16* __restrict__ Bt,
    const float* __restrict__ bias, void* __restrict__ out,
    int M, int N, int K) {
  constexpr int NWN = BN / WN;
  constexpr int MI = WM / 16, NI = WN / 16;
  __shared__ u16 As[2][BM * 64];
  __shared__ u16 Bs[2][BN * 64];
  const int tid = threadIdx.x, lane = tid & 63, wave = tid >> 6;
  const int m0 = blockIdx.y * BM, n0 = blockIdx.x * BN;
  const int wm = wave / NWN, wn = wave % NWN;
  const int g = lane >> 4, lr = lane & 15;
  const int srow = tid >> 3, sslot = tid & 7;  // staging: row-in-32-group, 16B slot

#define STAGE2(buf, k0) do {                                                        \
    _Pragma("unroll")                                                               \
    for (int i_ = 0; i_ < BM / 32; ++i_) {                                          \
      const int r_ = i_ * 32 + srow;                                                \
      gload_lds16(A + (size_t)(m0 + r_) * K + (k0) + ((sslot ^ (r_ & 7)) << 3),     \
                  &As[buf][i_ * 2048 + tid * 8]);                                   \
    }                                                                               \
    _Pragma("unroll")                                                               \
    for (int i_ = 0; i_ < BN / 32; ++i_) {                                          \
      const int r_ = i_ * 32 + srow;                                                \
      gload_lds16(Bt + (size_t)(n0 + r_) * K + (k0) + ((sslot ^ (r_ & 7)) << 3),    \
                  &Bs[buf][i_ * 2048 + tid * 8]);                                   \
    }                                                                               \
  } while (0)

  f32x4 acc[MI][NI] = {};
  const int kBeg = (SPLIT > 1) ? blockIdx.z * (K / SPLIT) : 0;
  const int NT = ((SPLIT > 1) ? K / SPLIT : K) >> 6;

  STAGE2(0, kBeg);
  STAGE2(1, kBeg + 64);
  asm volatile("s_waitcnt vmcnt(8)" ::: "memory");  // tile 0 landed; tile 1 in flight
  __builtin_amdgcn_s_barrier();
  asm volatile("" ::: "memory");

  for (int t = 0; t < NT; ++t) {
    const int cur = t & 1;
    bf16x8 af[MI][2], bf[NI][2];
#pragma unroll
    for (int step = 0; step < 2; ++step) {
#pragma unroll
      for (int mi = 0; mi < MI; ++mi) {
        const int r = wm * WM + mi * 16 + lr;
        af[mi][step] = *(const bf16x8*)&As[cur][r * 64 + ((((step << 2) + g) ^ (r & 7)) << 3)];
      }
#pragma unroll
      for (int ni = 0; ni < NI; ++ni) {
        const int r = wn * WN + ni * 16 + lr;
        bf[ni][step] = *(const bf16x8*)&Bs[cur][r * 64 + ((((step << 2) + g) ^ (r & 7)) << 3)];
      }
    }
    __builtin_amdgcn_s_setprio(1);
#pragma unroll
    for (int step = 0; step < 2; ++step)
#pragma unroll
      for (int mi = 0; mi < MI; ++mi)
#pragma unroll
        for (int ni = 0; ni < NI; ++ni)
          acc[mi][ni] = __builtin_amdgcn_mfma_f32_16x16x32_bf16(af[mi][step], bf[ni][step],
                                                                acc[mi][ni], 0, 0, 0);
    __builtin_amdgcn_s_setprio(0);
    asm volatile("s_waitcnt lgkmcnt(0)" ::: "memory");  // all our LDS reads retired
    __builtin_amdgcn_sched_barrier(0);
    __builtin_amdgcn_s_barrier();                       // whole block done reading buf[cur]
    asm volatile("" ::: "memory");
    if (t + 2 < NT) {
      STAGE2(cur, kBeg + (t + 2) * 64);                 // overwrite freed buffer
      asm volatile("s_waitcnt vmcnt(8)" ::: "memory");  // tile t+1 landed; t+2 in flight
    } else {
      asm volatile("s_waitcnt vmcnt(0)" ::: "memory");
    }
    __builtin_amdgcn_s_barrier();                       // collective: t+1 visible to all
    asm volatile("" ::: "memory");
  }
#undef STAGE2

  // epilogue: D layout col=lane&15, row=(lane>>4)*4+reg  [m89-verified]
#pragma unroll
  for (int mi = 0; mi < MI; ++mi) {
#pragma unroll
    for (int ni = 0; ni < NI; ++ni) {
      const int col = n0 + wn * WN + ni * 16 + lr;
      const float bv = (EPI == EPI_PART) ? 0.f : bias[col];
      f32x4 v = acc[mi][ni];
#pragma unroll
      for (int r = 0; r < 4; ++r) {
        const int row = m0 + wm * WM + mi * 16 + g * 4 + r;
        const float y = v[r] + bv;
        if (EPI == EPI_F32) {
          ((float*)out)[(size_t)row * N + col] = y;
        } else if (EPI == EPI_PART) {
          ((float*)out)[(size_t)blockIdx.z * M * N + (size_t)row * N + col] = y;
        } else if (EPI == EPI_BF16_RELU) {
          ((u16*)out)[(size_t)row * N + col] = f2bf(fmaxf(y, 0.f));
        } else {  // EPI_QKV
          u16* qb = (u16*)out;
          const int sec = col >> 9, cs = col & 511;
          const int b = row >> 10, tt = row & 1023, h = cs >> 6, d = cs & 63;
          if (sec == 0)
            qb[((size_t)((b * 8 + h) * 1024 + tt)) * 64 + d] = f2bf(y * QSCALE);
          else if (sec == 1)
            qb[4194304 + ((size_t)((b * 8 + h) * 1024 + tt)) * 64 + d] = f2bf(y);
          else
            qb[8388608 + ((size_t)((b * 8 + h) * 64 + d)) * 1024 + tt] = f2bf(y);
        }
      }
    }
  }
}

// ---------------------------- bf16 MFMA GEMM (m97-style) -------------------------
// Used for the N=512 split-K GEMMs (Wo, FFN2). Unchanged proven path.
template<int BM, int BN, int WM, int WN, int EPI, int SPLIT>
__global__ __launch_bounds__(256) void gemm_kernel(
    const u16* __restrict__ A, const u16* __restrict__ Bt,
    const float* __restrict__ bias, void* __restrict__ out,
    int M, int N, int K) {
  constexpr int NWN = BN / WN;
  constexpr int MI = WM / 16, NI = WN / 16;
  __shared__ u16 As[BM * 32];
  __shared__ u16 Bs[BN * 32];
  const int tid = threadIdx.x;
  const int lane = tid & 63;
  const int wave = tid >> 6;
  const int m0 = blockIdx.y * BM;
  const int n0 = blockIdx.x * BN;
  const int wm = wave / NWN, wn = wave % NWN;
  const int g = lane >> 4, lr = lane & 15;
  const int srow = lane >> 2, scol = (lane & 3) * 8;

  f32x4 acc[MI][NI] = {};

  const int kBeg = (SPLIT > 1) ? blockIdx.z * (K / SPLIT) : 0;
  const int kEnd = (SPLIT > 1) ? kBeg + (K / SPLIT) : K;
  for (int k0 = kBeg; k0 < kEnd; k0 += 32) {
#pragma unroll
    for (int ch = wave; ch < BM / 16; ch += 4)
      gload_lds16(A + (size_t)(m0 + ch * 16 + srow) * K + k0 + scol, &As[ch * 512]);
#pragma unroll
    for (int ch = wave; ch < BN / 16; ch += 4)
      gload_lds16(Bt + (size_t)(n0 + ch * 16 + srow) * K + k0 + scol, &Bs[ch * 512]);
    __syncthreads();
    bf16x8 a[MI], b[NI];
#pragma unroll
    for (int mi = 0; mi < MI; ++mi) a[mi] = *(const bf16x8*)&As[(wm * WM + mi * 16 + lr) * 32 + g * 8];
#pragma unroll
    for (int ni = 0; ni < NI; ++ni) b[ni] = *(const bf16x8*)&Bs[(wn * WN + ni * 16 + lr) * 32 + g * 8];
#pragma unroll
    for (int mi = 0; mi < MI; ++mi)
#pragma unroll
      for (int ni = 0; ni < NI; ++ni)
        acc[mi][ni] = __builtin_amdgcn_mfma_f32_16x16x32_bf16(a[mi], b[ni], acc[mi][ni], 0, 0, 0);
    __syncthreads();
  }

#pragma unroll
  for (int mi = 0; mi < MI; ++mi) {
#pragma unroll
    for (int ni = 0; ni < NI; ++ni) {
      const int col = n0 + wn * WN + ni * 16 + lr;
      const float bv = (EPI == EPI_PART) ? 0.f : bias[col];
      f32x4 v = acc[mi][ni];
#pragma unroll
      for (int r = 0; r < 4; ++r) {
        const int row = m0 + wm * WM + mi * 16 + g * 4 + r;
        const float y = v[r] + bv;
        if (EPI == EPI_F32) {
          ((float*)out)[(size_t)row * N + col] = y;
        } else if (EPI == EPI_PART) {
          ((float*)out)[(size_t)blockIdx.z * M * N + (size_t)row * N + col] = y;
        } else if (EPI == EPI_BF16_RELU) {
          ((u16*)out)[(size_t)row * N + col] = f2bf(fmaxf(y, 0.f));
        }
      }
    }
  }
}

// ------------- flash attention v4: LDS-staged K/V, double-buffered ---------------
__global__ __launch_bounds__(256, 2) void attn4_kernel(
    const u16* __restrict__ Q, const u16* __restrict__ K,
    const u16* __restrict__ Vt, u16* __restrict__ ctx) {
  __shared__ u16 smem[16384];
  const int tid = threadIdx.x, lane = tid & 63, w = tid >> 6;
  const int bh = blockIdx.x >> 3, qb = blockIdx.x & 7;
  const int c = lane & 31, g = lane >> 5;
  const int q0 = qb * 128 + w * 32;

  const u16* Qp = Q + ((size_t)bh * 1024 + q0 + c) * 64 + g * 8;
  const bf16x8 qf0 = *(const bf16x8*)(Qp);
  const bf16x8 qf1 = *(const bf16x8*)(Qp + 16);
  const bf16x8 qf2 = *(const bf16x8*)(Qp + 32);
  const bf16x8 qf3 = *(const bf16x8*)(Qp + 48);

  const u16* Kbase = K + (size_t)bh * 65536;
  const u16* Vbase = Vt + (size_t)bh * 65536;

  const int r0 = w * 16 + (lane >> 3), r1 = r0 + 8;
  const int cg0 = ((lane & 7) ^ (r0 & 7)) << 3;
  const int cg1 = ((lane & 7) ^ (r1 & 7)) << 3;

#define STAGE(buf, key0) do {                                                       \
    gload_lds16(Kbase + (size_t)((key0) + r0) * 64 + cg0, &smem[(buf)*4096 + w*1024]);       \
    gload_lds16(Kbase + (size_t)((key0) + r1) * 64 + cg1, &smem[(buf)*4096 + w*1024 + 512]); \
    gload_lds16(Vbase + (size_t)r0 * 1024 + (key0) + cg0, &smem[8192 + (buf)*4096 + w*1024]);\
    gload_lds16(Vbase + (size_t)r1 * 1024 + (key0) + cg1, &smem[8192 + (buf)*4096 + w*1024 + 512]); \
  } while (0)

  const int cs = c & 7;
  const int ro0 = c * 64, ro1 = (32 + c) * 64;
#define KS(buf, ro, cg) (*(const bf16x8*)&smem[(buf)*4096 + (ro) + ((((cg)) ^ cs) << 3)])
#define VS(buf, ro, cg) (*(const bf16x8*)&smem[8192 + (buf)*4096 + (ro) + ((((cg)) ^ cs) << 3)])

  f32x16 cacc[2] = {};
  float mrun = -1e30f, lrun = 0.f;

  STAGE(0, 0);
  __syncthreads();

  for (int kt = 0; kt < 16; ++kt) {
    const int buf = kt & 1;
    if (kt < 15) STAGE(buf ^ 1, (kt + 1) * 64);

    const bf16x8 kf0 = KS(buf, ro0, g),     kf1 = KS(buf, ro0, 2 + g);
    const bf16x8 kf2 = KS(buf, ro0, 4 + g), kf3 = KS(buf, ro0, 6 + g);
    const bf16x8 kf4 = KS(buf, ro1, g),     kf5 = KS(buf, ro1, 2 + g);
    const bf16x8 kf6 = KS(buf, ro1, 4 + g), kf7 = KS(buf, ro1, 6 + g);

    f32x16 sa = {}, sb = {};
    sa = __builtin_amdgcn_mfma_f32_32x32x16_bf16(kf0, qf0, sa, 0, 0, 0);
    sb = __builtin_amdgcn_mfma_f32_32x32x16_bf16(kf4, qf0, sb, 0, 0, 0);
    sa = __builtin_amdgcn_mfma_f32_32x32x16_bf16(kf1, qf1, sa, 0, 0, 0);
    sb = __builtin_amdgcn_mfma_f32_32x32x16_bf16(kf5, qf1, sb, 0, 0, 0);
    sa = __builtin_amdgcn_mfma_f32_32x32x16_bf16(kf2, qf2, sa, 0, 0, 0);
    sb = __builtin_amdgcn_mfma_f32_32x32x16_bf16(kf6, qf2, sb, 0, 0, 0);
    sa = __builtin_amdgcn_mfma_f32_32x32x16_bf16(kf3, qf3, sa, 0, 0, 0);
    sb = __builtin_amdgcn_mfma_f32_32x32x16_bf16(kf7, qf3, sb, 0, 0, 0);

    float tm[16];
#pragma unroll
    for (int r = 0; r < 16; ++r) tm[r] = fmaxf(sa[r], sb[r]);
#pragma unroll
    for (int st = 8; st >= 1; st >>= 1)
#pragma unroll
      for (int r = 0; r < st; ++r) tm[r] = fmaxf(tm[r], tm[r + st]);
    const float mt = fmaxf(tm[0], __shfl_xor(tm[0], 32));
    if (!__all(mt <= mrun)) {
      const float mnew = fmaxf(mrun, mt);
      const float al = fexp2(mrun - mnew);
#pragma unroll
      for (int r = 0; r < 16; ++r) { cacc[0][r] *= al; cacc[1][r] *= al; }
      lrun *= al;
      mrun = mnew;
    }
    float pa[16], pb[16];
#pragma unroll
    for (int r = 0; r < 16; ++r) pa[r] = fexp2(sa[r] - mrun);
#pragma unroll
    for (int r = 0; r < 16; ++r) pb[r] = fexp2(sb[r] - mrun);
    float ts[16];
#pragma unroll
    for (int r = 0; r < 16; ++r) ts[r] = pa[r] + pb[r];
#pragma unroll
    for (int st = 8; st >= 1; st >>= 1)
#pragma unroll
      for (int r = 0; r < st; ++r) ts[r] += ts[r + st];
    lrun += ts[0] + __shfl_xor(ts[0], 32);

    uint32_t wda[8], pwa[8], wdb[8], pwb[8];
#pragma unroll
    for (int i = 0; i < 8; ++i) wda[i] = cvt_pk_bf16(pa[2 * i], pa[2 * i + 1]);
#pragma unroll
    for (int i = 0; i < 8; ++i) wdb[i] = cvt_pk_bf16(pb[2 * i], pb[2 * i + 1]);
#pragma unroll
    for (int i = 0; i < 8; ++i) pwa[i] = __shfl_xor((int)wda[i], 32);
#pragma unroll
    for (int i = 0; i < 8; ++i) pwb[i] = __shfl_xor((int)wdb[i], 32);
    union { uint32_t u[4]; bf16x8 v; } b0a, b1a, b0b, b1b;
    const bool glo = (g == 0);
    b0a.u[0] = glo ? wda[0] : pwa[2]; b0a.u[1] = glo ? wda[1] : pwa[3];
    b0a.u[2] = glo ? pwa[0] : wda[2]; b0a.u[3] = glo ? pwa[1] : wda[3];
    b1a.u[0] = glo ? wda[4] : pwa[6]; b1a.u[1] = glo ? wda[5] : pwa[7];
    b1a.u[2] = glo ? pwa[4] : wda[6]; b1a.u[3] = glo ? pwa[5] : wda[7];
    b0b.u[0] = glo ? wdb[0] : pwb[2]; b0b.u[1] = glo ? wdb[1] : pwb[3];
    b0b.u[2] = glo ? pwb[0] : wdb[2]; b0b.u[3] = glo ? pwb[1] : wdb[3];
    b1b.u[0] = glo ? wdb[4] : pwb[6]; b1b.u[1] = glo ? wdb[5] : pwb[7];
    b1b.u[2] = glo ? pwb[4] : wdb[6]; b1b.u[3] = glo ? pwb[5] : wdb[7];

    const bf16x8 va00 = VS(buf, ro0, g),     va01 = VS(buf, ro0, 2 + g);
    const bf16x8 vb00 = VS(buf, ro0, 4 + g), vb01 = VS(buf, ro0, 6 + g);
    const bf16x8 va10 = VS(buf, ro1, g),     va11 = VS(buf, ro1, 2 + g);
    const bf16x8 vb10 = VS(buf, ro1, 4 + g), vb11 = VS(buf, ro1, 6 + g);

    cacc[0] = __builtin_amdgcn_mfma_f32_32x32x16_bf16(va00, b0a.v, cacc[0], 0, 0, 0);
    cacc[1] = __builtin_amdgcn_mfma_f32_32x32x16_bf16(va10, b0a.v, cacc[1], 0, 0, 0);
    cacc[0] = __builtin_amdgcn_mfma_f32_32x32x16_bf16(va01, b1a.v, cacc[0], 0, 0, 0);
    cacc[1] = __builtin_amdgcn_mfma_f32_32x32x16_bf16(va11, b1a.v, cacc[1], 0, 0, 0);
    cacc[0] = __builtin_amdgcn_mfma_f32_32x32x16_bf16(vb00, b0b.v, cacc[0], 0, 0, 0);
    cacc[1] = __builtin_amdgcn_mfma_f32_32x32x16_bf16(vb10, b0b.v, cacc[1], 0, 0, 0);
    cacc[0] = __builtin_amdgcn_mfma_f32_32x32x16_bf16(vb01, b1b.v, cacc[0], 0, 0, 0);
    cacc[1] = __builtin_amdgcn_mfma_f32_32x32x16_bf16(vb11, b1b.v, cacc[1], 0, 0, 0);

    __syncthreads();
  }

  const float inv = 1.0f / lrun;
  u16* tw = &smem[w * 2048];
#pragma unroll
  for (int h2 = 0; h2 < 2; ++h2) {
#pragma unroll
    for (int rq = 0; rq < 4; ++rq) {
      const u16 x0 = f2bf(cacc[h2][4 * rq + 0] * inv);
      const u16 x1 = f2bf(cacc[h2][4 * rq + 1] * inv);
      const u16 x2 = f2bf(cacc[h2][4 * rq + 2] * inv);
      const u16 x3 = f2bf(cacc[h2][4 * rq + 3] * inv);
      uint2 val;
      val.x = (uint32_t)x0 | ((uint32_t)x1 << 16);
      val.y = (uint32_t)x2 | ((uint32_t)x3 << 16);
      const int chunk = h2 * 4 + rq;
      *(uint2*)&tw[c * 64 + ((chunk ^ (c & 7)) * 8) + 4 * g] = val;
    }
  }
  __syncthreads();
  const int b_ = bh >> 3, h_ = bh & 7;
#pragma unroll
  for (int t = 0; t < 4; ++t) {
    const int lcg = t * 256 + tid;
    const int wv = lcg >> 8, rem = lcg & 255;
    const int q = rem >> 3, cg = rem & 7;
    const uint4 val = *(const uint4*)&smem[wv * 2048 + q * 64 + ((cg ^ (q & 7)) * 8)];
    const int grow = qb * 128 + wv * 32 + q;
    *(uint4*)&ctx[((size_t)(b_ * 1024 + grow)) * 512 + h_ * 64 + cg * 8] = val;
  }
#undef STAGE
#undef KS
#undef VS
}

// ------- residual + split-K-combine + layernorm (1 wave per 512-col row) --------
template<bool ABF16>
__global__ __launch_bounds__(256) void lnc_kernel(
    const void* __restrict__ Av, const float* __restrict__ P0,
    const float* __restrict__ P1, const float* __restrict__ pb,
    const float* __restrict__ gw, const float* __restrict__ bw,
    float* __restrict__ outF, u16* __restrict__ outB) {
  const int lane = threadIdx.x & 63, wave = threadIdx.x >> 6;
  const int row = blockIdx.x * 4 + wave;
  float a[8];
  if (ABF16) {
    const uint4 q = ((const uint4*)((const u16*)Av + (size_t)row * 512))[lane];
    const u16* pu = (const u16*)&q;
#pragma unroll
    for (int j = 0; j < 8; ++j) a[j] = __uint_as_float((uint32_t)pu[j] << 16);
  } else {
    const float4* a4 = (const float4*)((const float*)Av + (size_t)row * 512);
    const float4 x0 = a4[lane * 2], x1 = a4[lane * 2 + 1];
    a[0] = x0.x; a[1] = x0.y; a[2] = x0.z; a[3] = x0.w;
    a[4] = x1.x; a[5] = x1.y; a[6] = x1.z; a[7] = x1.w;
  }
  const float4* p04 = (const float4*)(P0 + (size_t)row * 512);
  const float4* p14 = (const float4*)(P1 + (size_t)row * 512);
  const float4 q00 = p04[lane * 2], q01 = p04[lane * 2 + 1];
  const float4 q10 = p14[lane * 2], q11 = p14[lane * 2 + 1];
  const float4 e0 = ((const float4*)pb)[lane * 2], e1 = ((const float4*)pb)[lane * 2 + 1];
  float v[8] = {a[0] + q00.x + q10.x + e0.x, a[1] + q00.y + q10.y + e0.y,
                a[2] + q00.z + q10.z + e0.z, a[3] + q00.w + q10.w + e0.w,
                a[4] + q01.x + q11.x + e1.x, a[5] + q01.y + q11.y + e1.y,
                a[6] + q01.z + q11.z + e1.z, a[7] + q01.w + q11.w + e1.w};
  float s = 0.f;
#pragma unroll
  for (int j = 0; j < 8; ++j) s += v[j];
#pragma unroll
  for (int off = 32; off >= 1; off >>= 1) s += __shfl_xor(s, off);
  const float mu = s * (1.f / 512.f);
  float vs = 0.f;
#pragma unroll
  for (int j = 0; j < 8; ++j) { const float d = v[j] - mu; vs += d * d; }
#pragma unroll
  for (int off = 32; off >= 1; off >>= 1) vs += __shfl_xor(vs, off);
  const float rstd = rsqrtf(vs * (1.f / 512.f) + 1e-5f);
  const float4 gA = ((const float4*)gw)[lane * 2], gB = ((const float4*)gw)[lane * 2 + 1];
  const float4 bA = ((const float4*)bw)[lane * 2], bB = ((const float4*)bw)[lane * 2 + 1];
  const float og[8] = {gA.x, gA.y, gA.z, gA.w, gB.x, gB.y, gB.z, gB.w};
  const float ob[8] = {bA.x, bA.y, bA.z, bA.w, bB.x, bB.y, bB.z, bB.w};
  float o[8];
#pragma unroll
  for (int j = 0; j < 8; ++j) o[j] = (v[j] - mu) * rstd * og[j] + ob[j];
  if (outF) {
    float4 w0 = {o[0], o[1], o[2], o[3]}, w1 = {o[4], o[5], o[6], o[7]};
    ((float4*)(outF + (size_t)row * 512))[lane * 2] = w0;
    ((float4*)(outF + (size_t)row * 512))[lane * 2 + 1] = w1;
  }
  if (outB) {
    union { u16 u[8]; uint4 q; } pk;
#pragma unroll
    for (int j = 0; j < 8; ++j) pk.u[j] = f2bf(o[j]);
    ((uint4*)(outB + (size_t)row * 512))[lane] = pk.q;
  }
}

// --------------------------------- launch ---------------------------------------
extern "C" void kernel_launch(void* const* d_in, const int* in_sizes, int n_in,
                              void* d_out, int out_size, void* d_ws, size_t ws_size,
                              hipStream_t stream) {
  const float* x   = (const float*)d_in[0];
  const float* Wq  = (const float*)d_in[1];
  const float* bq  = (const float*)d_in[2];
  const float* Wk  = (const float*)d_in[3];
  const float* bk  = (const float*)d_in[4];
  const float* Wv  = (const float*)d_in[5];
  const float* bv  = (const float*)d_in[6];
  const float* Wo  = (const float*)d_in[7];
  const float* bo  = (const float*)d_in[8];
  const float* g1  = (const float*)d_in[9];
  const float* b1  = (const float*)d_in[10];
  const float* g2  = (const float*)d_in[11];
  const float* b2  = (const float*)d_in[12];
  const float* W1  = (const float*)d_in[13];
  const float* bf1 = (const float*)d_in[14];
  const float* W2  = (const float*)d_in[15];
  const float* bf2 = (const float*)d_in[16];

  char* ws = (char*)d_ws;
  u16*   xb    = (u16*)(ws + 0);           // [8192][512] bf16
  u16*   Wqkvt = (u16*)(ws + 8388608);     // [1536][512] bf16
  u16*   Wot   = (u16*)(ws + 9961472);     // [512][512]
  u16*   W1t   = (u16*)(ws + 10485760);    // [2048][512]
  u16*   W2t   = (u16*)(ws + 12582912);    // [512][2048]
  u16*   Qb    = (u16*)(ws + 14680064);    // [BH][1024][64]; Kb,Vtb follow
  u16*   ctx   = (u16*)(ws + 39845888);    // [8192][512] bf16
  float* P0    = (float*)(ws + 48234496);  // [8192][512] f32 partial (P1 follows)
  u16*   h1b   = (u16*)(ws + 81788928);    // [8192][512] bf16
  u16*   mid   = (u16*)(ws + 14680064);    // [8192][2048] bf16 (over Qb..ctx, dead)
  float* bqkv  = (float*)(ws + 39845888);  // 1536 f32 (over ctx, dead before attn)

  prep_kernel<<<5126, 256, 0, stream>>>(x, xb, Wq, Wk, Wv, Wo, Wqkvt, Wot,
                                        W1, W1t, W2, W2t, bq, bk, bv, bqkv);

  // fused QKV projection (pipelined GEMM; Q pre-scaled by 1/sqrt(D)*log2e)
  gemm2_kernel<128, 128, 64, 64, EPI_QKV, 1><<<dim3(12, 64), 256, 0, stream>>>(
      xb, Wqkvt, bqkv, Qb, 8192, 1536, 512);

  attn4_kernel<<<512, 256, 0, stream>>>(Qb, Qb + 4194304, Qb + 8388608, ctx);

  // Wo: split-K x2 partials; LN1 combines xb + P0 + P1 + bo -> h1b (bf16)
  gemm_kernel<64, 128, 64, 32, EPI_PART, 2><<<dim3(4, 128, 2), 256, 0, stream>>>(
      ctx, Wot, nullptr, P0, 8192, 512, 512);
  lnc_kernel<true><<<2048, 256, 0, stream>>>(xb, P0, P0 + 4194304, bo, g1, b1,
                                             nullptr, h1b);

  // FFN1 (pipelined GEMM)
  gemm2_kernel<128, 128, 64, 64, EPI_BF16_RELU, 1><<<dim3(16, 64), 256, 0, stream>>>(
      h1b, W1t, bf1, mid, 8192, 2048, 512);

  // FFN2: split-K x2 partials; LN2 combines h1b + P0 + P1 + bf2 -> d_out (f32)
  gemm_kernel<64, 128, 64, 32, EPI_PART, 2><<<dim3(4, 128, 2), 256, 0, stream>>>(
      mid, W2t, nullptr, P0, 8192, 512, 2048);
  lnc_kernel<true><<<2048, 256, 0, stream>>>(h1b, P0, P0 + 4194304, bf2, g2, b2,
                                             (float*)d_out, nullptr);
}